// Round 1
// baseline (24209.590 us; speedup 1.0000x reference)
//
#include <hip/hip_runtime.h>
#include <math.h>

#define NN 104960      // nodes
#define OUT 200
#define EMB 101
#define NPG 205
#define BATCH 512
#define NE 629760      // edges
#define LAYERS 6

// ---------------- utility kernels ----------------
__global__ void zero_i32(int* p, int n){ int i=blockIdx.x*256+threadIdx.x; if(i<n) p[i]=0; }
__global__ void zero_f32(float* p, int n){ int i=blockIdx.x*blockDim.x+threadIdx.x; if(i<n) p[i]=0.f; }
__global__ void copy_i32(const int* __restrict__ a, int* __restrict__ b, int n){
  int i=blockIdx.x*256+threadIdx.x; if(i<n) b[i]=a[i];
}

// h[N,200] = pad(x[N,101])
__global__ void pad_kernel(const float* __restrict__ x, float* __restrict__ h) {
  int idx = blockIdx.x*256 + threadIdx.x;          // N*OUT = 20,992,000
  if (idx >= NN*OUT) return;
  int n = idx / OUT, j = idx - n*OUT;
  h[idx] = (j < EMB) ? x[n*EMB + j] : 0.f;
}

// Wf[i][k][o] = sum_j ggc_w[i][k][j] * wih[o][j]   (i<6, k<200, o<600)
__global__ void fuse_w_kernel(const float* __restrict__ ggc_w, const float* __restrict__ wih,
                              float* __restrict__ Wf) {
  long idx = (long)blockIdx.x*256 + threadIdx.x;
  if (idx >= 6L*200*600) return;
  int o = (int)(idx % 600); long r = idx / 600; int k = (int)(r % 200); int i = (int)(r / 200);
  const float* wr = ggc_w + ((long)i*200 + k)*200;
  const float* vr = wih + (long)o*200;
  float acc = 0.f;
  for (int j=0;j<200;j++) acc += wr[j]*vr[j];
  Wf[idx] = acc;
}

// whhT[k*600+o] = whh[o*200+k]
__global__ void transpose_whh(const float* __restrict__ whh, float* __restrict__ whhT) {
  int idx = blockIdx.x*256 + threadIdx.x;
  if (idx >= 600*200) return;
  int k = idx % 200, o = idx / 200;
  whhT[(long)k*600 + o] = whh[idx];
}

// ---------------- CSR build ----------------
__global__ void count_deg(const int* __restrict__ ei, int* __restrict__ cnt) {
  int e = blockIdx.x*256+threadIdx.x;
  if (e < NE) atomicAdd(&cnt[ei[NE + e]], 1);    // dst row
}

__global__ __launch_bounds__(1024) void scan_kernel(const int* __restrict__ cnt, int* __restrict__ rowptr) {
  __shared__ int sdata[1024];
  __shared__ int s_off;
  int tid = threadIdx.x;
  if (tid==0) s_off = 0;
  __syncthreads();
  for (int base=0; base<NN; base+=1024) {
    int i = base + tid;
    int v = (i<NN)? cnt[i] : 0;
    sdata[tid] = v;
    __syncthreads();
    for (int d=1; d<1024; d<<=1) {
      int t = (tid>=d)? sdata[tid-d] : 0;
      __syncthreads();
      sdata[tid] += t;
      __syncthreads();
    }
    if (i<NN) rowptr[i] = s_off + sdata[tid] - v;   // exclusive
    __syncthreads();
    if (tid==1023) s_off += sdata[1023];
    __syncthreads();
  }
  if (tid==0) rowptr[NN] = s_off;
}

__global__ void fill_csr(const int* __restrict__ ei, int* __restrict__ cursor, int* __restrict__ col) {
  int e = blockIdx.x*256+threadIdx.x;
  if (e < NE) {
    int dst = ei[NE+e], src = ei[e];
    int pos = atomicAdd(&cursor[dst], 1);
    col[pos] = src;
  }
}

// hagg[n,:] = sum_{e in row(n)} h[col[e],:]   one wave per node
__global__ __launch_bounds__(256) void gather_kernel(const float* __restrict__ h,
        const int* __restrict__ rowptr, const int* __restrict__ col, float* __restrict__ out) {
  int wave = threadIdx.x >> 6;
  int lane = threadIdx.x & 63;
  int n = blockIdx.x*4 + wave;
  if (n >= NN) return;
  float a0=0.f,a1=0.f,a2=0.f,a3=0.f;
  int s = rowptr[n], e = rowptr[n+1];
  for (int p=s; p<e; ++p) {
    const float* hr = h + (long)col[p]*OUT;
    a0 += hr[lane]; a1 += hr[lane+64]; a2 += hr[lane+128];
    if (lane < 8) a3 += hr[lane+192];
  }
  float* o = out + (long)n*OUT;
  o[lane]=a0; o[lane+64]=a1; o[lane+128]=a2; if (lane<8) o[lane+192]=a3;
}

// ---------------- fused GRU (two [N,200]x[200,600] GEMMs + gates) ----------------
// gi = hagg @ Wf (Wf = ggc_w[i] @ wih.T, [200,600]),  gh = h @ whhT ([200,600])
__global__ __launch_bounds__(256) void gru_kernel(
    const float* __restrict__ hagg, const float* __restrict__ h,
    const float* __restrict__ Wf, const float* __restrict__ whhT,
    const float* __restrict__ bih, const float* __restrict__ bhh,
    float* __restrict__ hnew) {
  __shared__ float Aa[16][72];     // k-major, 32B-aligned rows for b128 reads
  __shared__ float Ah[16][72];
  __shared__ float Bs[6][16][33];
  int bm = blockIdx.x * 64;
  int bn = blockIdx.y * 32;
  int tx = threadIdx.x & 31;       // output col j
  int ty = threadIdx.x >> 5;       // 0..7 -> rows ty*8..ty*8+7
  float acc[8][6];
  #pragma unroll
  for (int i=0;i<8;i++)
    #pragma unroll
    for (int g=0;g<6;g++) acc[i][g]=0.f;

  for (int k0=0;k0<OUT;k0+=16) {
    #pragma unroll
    for (int q=0;q<4;q++){
      int idx = threadIdx.x + q*256;
      int r = idx >> 4, c = idx & 15;
      int kk = k0 + c;
      float va=0.f, vh=0.f;
      if (kk<OUT){ va = hagg[(long)(bm+r)*OUT + kk]; vh = h[(long)(bm+r)*OUT + kk]; }
      Aa[c][r]=va; Ah[c][r]=vh;
    }
    #pragma unroll
    for (int q=0;q<12;q++){
      int idx = threadIdx.x + q*256;    // 0..3071
      int g = idx / 512;
      int rem = idx & 511;
      int c = rem >> 5;
      int j = rem & 31;
      int kk = k0 + c; int jj = bn + j;
      float v = 0.f;
      if (kk<OUT && jj<OUT)
        v = (g<3) ? Wf[(long)kk*600 + g*200 + jj]
                  : whhT[(long)kk*600 + (g-3)*200 + jj];
      Bs[g][c][j] = v;
    }
    __syncthreads();
    #pragma unroll
    for (int kk=0;kk<16;kk++){
      float bv[6];
      #pragma unroll
      for (int g=0;g<6;g++) bv[g] = Bs[g][kk][tx];
      #pragma unroll
      for (int i=0;i<8;i++){
        float aa = Aa[kk][ty*8+i];
        float ah = Ah[kk][ty*8+i];
        acc[i][0] += aa*bv[0]; acc[i][1] += aa*bv[1]; acc[i][2] += aa*bv[2];
        acc[i][3] += ah*bv[3]; acc[i][4] += ah*bv[4]; acc[i][5] += ah*bv[5];
      }
    }
    __syncthreads();
  }
  int j = bn + tx;
  if (j < OUT) {
    float bri = bih[j],      brh = bhh[j];
    float bzi = bih[OUT+j],  bzh = bhh[OUT+j];
    float bni = bih[2*OUT+j],bnh = bhh[2*OUT+j];
    #pragma unroll
    for (int i=0;i<8;i++){
      long row = bm + ty*8 + i;
      float r = 1.f/(1.f+expf(-(acc[i][0]+bri + acc[i][3]+brh)));
      float z = 1.f/(1.f+expf(-(acc[i][1]+bzi + acc[i][4]+bzh)));
      float nn = tanhf(acc[i][2]+bni + r*(acc[i][5]+bnh));
      float hv = h[row*OUT + j];
      hnew[row*OUT + j] = (1.f-z)*nn + z*hv;
    }
  }
}

// ---------------- head ----------------
// conv1d over length dim, channels = NPG=205, k=3 pad=1.
// input[b,p,l]: l<200 -> hid[(b*205+p)*200+l]; else x[(b*205+p)*101+(l-200)]
__global__ __launch_bounds__(256) void conv1_kernel(const float* __restrict__ hid,
        const float* __restrict__ x, const float* __restrict__ w, const float* __restrict__ bias,
        int LIN, float* __restrict__ out) {
  __shared__ float sm[NPG][66];
  int b = blockIdx.y;
  int t0 = blockIdx.x * 64;
  for (int idx = threadIdx.x; idx < NPG*66; idx += 256) {
    int p = idx / 66, c = idx - p*66;
    int l = t0 - 1 + c;
    float v = 0.f;
    if (l >= 0 && l < LIN) {
      long node = (long)b*NPG + p;
      v = (l < OUT) ? hid[node*OUT + l] : x[node*EMB + (l-OUT)];
    }
    sm[p][c] = v;
  }
  __syncthreads();
  int tl = threadIdx.x & 63;
  int og = threadIdx.x >> 6;          // wave-uniform
  int t = t0 + tl;
  if (t >= LIN) return;
  for (int o = og; o < 50; o += 4) {
    float acc = bias[o];
    const float* wr = w + o*NPG*3;
    for (int p = 0; p < NPG; ++p) {
      acc += wr[p*3+0]*sm[p][tl] + wr[p*3+1]*sm[p][tl+1] + wr[p*3+2]*sm[p][tl+2];
    }
    out[((long)b*50 + o)*LIN + t] = acc;
  }
}

// per-channel sum/sumsq over [512, C, L]
__global__ void bn_stats(const float* __restrict__ v, int C, int L, float* __restrict__ sums) {
  int c = blockIdx.x;
  int bs = blockIdx.y * 32;
  float s = 0.f, s2 = 0.f;
  for (int idx = threadIdx.x; idx < 32*L; idx += 256) {
    int b = bs + idx / L, t = idx - (idx/L)*L;
    float val = v[((long)b*C + c)*L + t];
    s += val; s2 += val*val;
  }
  __shared__ float rs[256], rq[256];
  rs[threadIdx.x]=s; rq[threadIdx.x]=s2; __syncthreads();
  for (int d=128; d>0; d>>=1){
    if (threadIdx.x<d){ rs[threadIdx.x]+=rs[threadIdx.x+d]; rq[threadIdx.x]+=rq[threadIdx.x+d]; }
    __syncthreads();
  }
  if (threadIdx.x==0){ atomicAdd(&sums[2*c], rs[0]); atomicAdd(&sums[2*c+1], rq[0]); }
}

__global__ void bn_finalize(const float* __restrict__ sums, const float* __restrict__ g,
        const float* __restrict__ b, int C, float inv_n, float* __restrict__ scale, float* __restrict__ shift) {
  int c = threadIdx.x;
  if (c < C) {
    float mean = sums[2*c]*inv_n;
    float var = sums[2*c+1]*inv_n - mean*mean;
    float sc = g[c]*rsqrtf(var + 1e-5f);
    scale[c] = sc;
    shift[c] = b[c] - mean*sc;
  }
}

// BN (+ optional LeakyReLU) + maxpool(K, stride 2)
__global__ void bn_act_pool(const float* __restrict__ v, const float* __restrict__ sc,
      const float* __restrict__ sh, int C, int Lin, int Lout, int K, int do_relu, float* __restrict__ out) {
  int idx = blockIdx.x*256 + threadIdx.x;
  int total = BATCH*C*Lout;
  if (idx>=total) return;
  int t = idx % Lout; int r = idx / Lout; int c = r % C; int b = r / C;
  const float* src = v + ((long)(b*C + c))*Lin + 2*t;
  float m = -3.4e38f;
  for (int k=0;k<K;k++){
    float u = src[k]*sc[c] + sh[c];
    if (do_relu) u = (u>=0.f)? u : 0.01f*u;
    m = fmaxf(m,u);
  }
  out[idx] = m;
}

// conv2: k=1, pad=1 -> out[b,c,t], t in [0,Lm+2); borders are bias-only
__global__ __launch_bounds__(256) void conv2_kernel(const float* __restrict__ in,
        const float* __restrict__ w, const float* __restrict__ b2, int Lm, float* __restrict__ out) {
  __shared__ float sw[1000];
  __shared__ float sin[50*150];
  int b = blockIdx.x;
  for (int i=threadIdx.x;i<1000;i+=256) sw[i]=w[i];
  for (int i=threadIdx.x;i<50*Lm;i+=256) sin[i] = in[(long)b*50*Lm + i];
  __syncthreads();
  int Lo = Lm + 2;
  for (int idx=threadIdx.x; idx<20*Lo; idx+=256) {
    int c = idx / Lo, t = idx - c*Lo;
    float acc = b2[c];
    if (t>=1 && t<=Lm) {
      const float* sp = sin + (t-1);
      const float* wp = sw + c*50;
      for (int i=0;i<50;i++) acc += wp[i]*sp[i*Lm];
    }
    out[(long)b*20*Lo + idx] = acc;
  }
}

__global__ void final_kernel(const float* __restrict__ Zf, const float* __restrict__ Yf,
        const float* __restrict__ fc1w, const float* __restrict__ fc1b,
        const float* __restrict__ fc2w, const float* __restrict__ fc2b, float* __restrict__ out) {
  int b = blockIdx.x;
  float s1=0.f, s2=0.f;
  for (int i=threadIdx.x;i<1520;i+=256) s1 += Zf[(long)b*1520+i]*fc1w[i];
  for (int i=threadIdx.x;i<1000;i+=256) s2 += Yf[(long)b*1000+i]*fc2w[i];
  __shared__ float r1[256], r2[256];
  r1[threadIdx.x]=s1; r2[threadIdx.x]=s2; __syncthreads();
  for (int d=128; d>0; d>>=1){
    if (threadIdx.x<d){ r1[threadIdx.x]+=r1[threadIdx.x+d]; r2[threadIdx.x]+=r2[threadIdx.x+d]; }
    __syncthreads();
  }
  if (threadIdx.x==0){
    float res = (r1[0]+fc1b[0])*(r2[0]+fc2b[0]);
    out[b] = 1.f/(1.f+expf(-res));
  }
}

// ---------------- launch ----------------
extern "C" void kernel_launch(void* const* d_in, const int* in_sizes, int n_in,
                              void* d_out, int out_size, void* d_ws, size_t ws_size,
                              hipStream_t stream) {
  const float* x    = (const float*)d_in[0];
  const int*   ei   = (const int*)d_in[1];
  const float* ggcw = (const float*)d_in[2];
  const float* wih  = (const float*)d_in[3];
  const float* whh  = (const float*)d_in[4];
  const float* bih  = (const float*)d_in[5];
  const float* bhh  = (const float*)d_in[6];
  const float* c1w  = (const float*)d_in[7];
  const float* c1b  = (const float*)d_in[8];
  const float* bn1g = (const float*)d_in[9];
  const float* bn1b = (const float*)d_in[10];
  const float* c2w  = (const float*)d_in[11];
  const float* c2b  = (const float*)d_in[12];
  const float* bn2g = (const float*)d_in[13];
  const float* bn2b = (const float*)d_in[14];
  const float* fc1w = (const float*)d_in[15];
  const float* fc1b = (const float*)d_in[16];
  const float* fc2w = (const float*)d_in[17];
  const float* fc2b = (const float*)d_in[18];
  float* out = (float*)d_out;

  char* ws = (char*)d_ws;
  size_t HS = (size_t)NN*OUT*sizeof(float);            // 83,968,000
  float* buf0 = (float*)ws;
  float* buf1 = (float*)(ws + HS);
  float* buf2 = (float*)(ws + 2*HS);
  char* aux = ws + 3*HS;
  float* Wf   = (float*)aux;  aux += (size_t)6*200*600*4;
  float* whhT = (float*)aux;  aux += (size_t)200*600*4;
  int* rowptr = (int*)aux;    aux += (size_t)(NN+1)*4;
  int* cursor = (int*)aux;    aux += (size_t)NN*4;
  int* col    = (int*)aux;    aux += (size_t)NE*4;
  float* sums = (float*)aux;  aux += 128*4;
  float* sc   = (float*)aux;  aux += 64*4;
  float* sh   = (float*)aux;  aux += 64*4;
  // head overlays (GGC scratch buffers are free by then)
  float* z_c1  = buf1;
  float* y_c1  = z_c1  + (size_t)512*50*301;
  float* z_mp1 = y_c1  + (size_t)512*50*200;
  float* y_mp1 = z_mp1 + (size_t)512*50*150;
  float* z_c2  = buf2;
  float* y_c2  = z_c2  + (size_t)512*20*152;
  float* z_mp2 = y_c2  + (size_t)512*20*101;
  float* y_mp2 = z_mp2 + (size_t)512*1520;

  // init + precompute
  pad_kernel<<<NN*OUT/256, 256, 0, stream>>>(x, buf0);
  fuse_w_kernel<<<(6*200*600+255)/256, 256, 0, stream>>>(ggcw, wih, Wf);
  transpose_whh<<<(600*200+255)/256, 256, 0, stream>>>(whh, whhT);
  // CSR
  zero_i32<<<(NN+255)/256, 256, 0, stream>>>(cursor, NN);
  count_deg<<<NE/256, 256, 0, stream>>>(ei, cursor);
  scan_kernel<<<1, 1024, 0, stream>>>(cursor, rowptr);
  copy_i32<<<(NN+255)/256, 256, 0, stream>>>(rowptr, cursor, NN);
  fill_csr<<<NE/256, 256, 0, stream>>>(ei, cursor, col);

  // GGC layers
  float* cur = buf0; float* hb = buf1; float* other = buf2;
  for (int i=0;i<LAYERS;i++){
    gather_kernel<<<NN/4, 256, 0, stream>>>(cur, rowptr, col, hb);
    gru_kernel<<<dim3(NN/64, 7), 256, 0, stream>>>(hb, cur, Wf + (long)i*200*600, whhT,
                                                   bih, bhh, other);
    float* t = cur; cur = other; other = t;
  }
  // cur == buf0 (final hidden); buf1/buf2 free for head

  // head
  conv1_kernel<<<dim3(5, BATCH), 256, 0, stream>>>(cur, x, c1w, c1b, 301, z_c1);
  conv1_kernel<<<dim3(4, BATCH), 256, 0, stream>>>(cur, x, c1w, c1b, 200, y_c1);

  zero_f32<<<1, 128, 0, stream>>>(sums, 128);
  bn_stats<<<dim3(50,16), 256, 0, stream>>>(z_c1, 50, 301, sums);
  bn_finalize<<<1, 64, 0, stream>>>(sums, bn1g, bn1b, 50, 1.f/(512.f*301.f), sc, sh);
  bn_act_pool<<<(512*50*150+255)/256, 256, 0, stream>>>(z_c1, sc, sh, 50, 301, 150, 3, 1, z_mp1);

  zero_f32<<<1, 128, 0, stream>>>(sums, 128);
  bn_stats<<<dim3(50,16), 256, 0, stream>>>(y_c1, 50, 200, sums);
  bn_finalize<<<1, 64, 0, stream>>>(sums, bn1g, bn1b, 50, 1.f/(512.f*200.f), sc, sh);
  bn_act_pool<<<(512*50*99+255)/256, 256, 0, stream>>>(y_c1, sc, sh, 50, 200, 99, 3, 1, y_mp1);

  conv2_kernel<<<BATCH, 256, 0, stream>>>(z_mp1, c2w, c2b, 150, z_c2);
  conv2_kernel<<<BATCH, 256, 0, stream>>>(y_mp1, c2w, c2b, 99, y_c2);

  zero_f32<<<1, 128, 0, stream>>>(sums, 128);
  bn_stats<<<dim3(20,16), 256, 0, stream>>>(z_c2, 20, 152, sums);
  bn_finalize<<<1, 64, 0, stream>>>(sums, bn2g, bn2b, 20, 1.f/(512.f*152.f), sc, sh);
  bn_act_pool<<<(512*20*76+255)/256, 256, 0, stream>>>(z_c2, sc, sh, 20, 152, 76, 2, 0, z_mp2);

  zero_f32<<<1, 128, 0, stream>>>(sums, 128);
  bn_stats<<<dim3(20,16), 256, 0, stream>>>(y_c2, 20, 101, sums);
  bn_finalize<<<1, 64, 0, stream>>>(sums, bn2g, bn2b, 20, 1.f/(512.f*101.f), sc, sh);
  bn_act_pool<<<(512*20*50+255)/256, 256, 0, stream>>>(y_c2, sc, sh, 20, 101, 50, 2, 0, y_mp2);

  final_kernel<<<BATCH, 256, 0, stream>>>(z_mp2, y_mp2, fc1w, fc1b, fc2w, fc2b, out);
}

// Round 2
// 3865.177 us; speedup vs baseline: 6.2635x; 6.2635x over previous
//
#include <hip/hip_runtime.h>
#include <math.h>

#define NN 104960      // nodes
#define OUT 200
#define EMB 101
#define NPG 205
#define BATCH 512
#define NE 629760      // edges
#define LAYERS 6

typedef _Float16 h8 __attribute__((ext_vector_type(8)));
typedef float f4 __attribute__((ext_vector_type(4)));

// ---------------- utility kernels ----------------
__global__ void zero_i32(int* p, int n){ int i=blockIdx.x*256+threadIdx.x; if(i<n) p[i]=0; }
__global__ void zero_f32(float* p, int n){ int i=blockIdx.x*blockDim.x+threadIdx.x; if(i<n) p[i]=0.f; }
__global__ void copy_i32(const int* __restrict__ a, int* __restrict__ b, int n){
  int i=blockIdx.x*256+threadIdx.x; if(i<n) b[i]=a[i];
}

// h[N,200] fp16 = pad(x[N,101])
__global__ void pad16(const float* __restrict__ x, _Float16* __restrict__ h) {
  int idx = blockIdx.x*256 + threadIdx.x;
  if (idx >= NN*OUT) return;
  int n = idx / OUT, j = idx - n*OUT;
  h[idx] = (j < EMB) ? (_Float16)x[n*EMB + j] : (_Float16)0.f;
}

// Wf[i][k][o] = sum_j ggc_w[i][k][j] * wih[o][j]   (i<6, k<200, o<600)  fp32
__global__ void fuse_w_kernel(const float* __restrict__ ggc_w, const float* __restrict__ wih,
                              float* __restrict__ Wf) {
  long idx = (long)blockIdx.x*256 + threadIdx.x;
  if (idx >= 6L*200*600) return;
  int o = (int)(idx % 600); long r = idx / 600; int k = (int)(r % 200); int i = (int)(r / 200);
  const float* wr = ggc_w + ((long)i*200 + k)*200;
  const float* vr = wih + (long)o*200;
  float acc = 0.f;
  for (int j=0;j<200;j++) acc += wr[j]*vr[j];
  Wf[idx] = acc;
}

// Bp[layer][gate][s][j(208)][kk(32)] fp16, fragment-order B for MFMA.
// gate<3: B[k][g*200+j] = Wf_l[k*600+g*200+j]; gate>=3: = whh[((g-3)*200+j)*200+k]
__global__ void pack_b(const float* __restrict__ Wf, const float* __restrict__ whh,
                       _Float16* __restrict__ Bp) {
  size_t idx = (size_t)blockIdx.x*256 + threadIdx.x;
  if (idx >= 6UL*6*7*208*32) return;
  int kk = (int)(idx & 31); size_t r = idx >> 5;
  int j = (int)(r % 208); r /= 208;
  int s = (int)(r % 7);   r /= 7;
  int g = (int)(r % 6);   int l = (int)(r / 6);
  int k = s*32 + kk;
  float v = 0.f;
  if (k < 200 && j < 200) {
    v = (g < 3) ? Wf[(size_t)l*120000 + (size_t)k*600 + g*200 + j]
                : whh[((size_t)(g-3)*200 + j)*200 + k];
  }
  Bp[idx] = (_Float16)v;
}

// ---------------- CSR build ----------------
__global__ void count_deg(const int* __restrict__ ei, int* __restrict__ cnt) {
  int e = blockIdx.x*256+threadIdx.x;
  if (e < NE) atomicAdd(&cnt[ei[NE + e]], 1);
}

__global__ __launch_bounds__(1024) void scan_kernel(const int* __restrict__ cnt, int* __restrict__ rowptr) {
  __shared__ int sdata[1024];
  __shared__ int s_off;
  int tid = threadIdx.x;
  if (tid==0) s_off = 0;
  __syncthreads();
  for (int base=0; base<NN; base+=1024) {
    int i = base + tid;
    int v = (i<NN)? cnt[i] : 0;
    sdata[tid] = v;
    __syncthreads();
    for (int d=1; d<1024; d<<=1) {
      int t = (tid>=d)? sdata[tid-d] : 0;
      __syncthreads();
      sdata[tid] += t;
      __syncthreads();
    }
    if (i<NN) rowptr[i] = s_off + sdata[tid] - v;
    __syncthreads();
    if (tid==1023) s_off += sdata[1023];
    __syncthreads();
  }
  if (tid==0) rowptr[NN] = s_off;
}

__global__ void fill_csr(const int* __restrict__ ei, int* __restrict__ cursor, int* __restrict__ col) {
  int e = blockIdx.x*256+threadIdx.x;
  if (e < NE) {
    int dst = ei[NE+e], src = ei[e];
    int pos = atomicAdd(&cursor[dst], 1);
    col[pos] = src;
  }
}

// hagg[n,:] += h[col,:] ; thread = (node, 8-elem chunk), 25 chunks/node
__global__ void gather16(const _Float16* __restrict__ h, const int* __restrict__ rowptr,
                         const int* __restrict__ col, _Float16* __restrict__ out) {
  int idx = blockIdx.x*256 + threadIdx.x;
  if (idx >= NN*25) return;
  int n = idx / 25, c = idx - n*25;
  int s = rowptr[n], e = rowptr[n+1];
  float a[8];
  #pragma unroll
  for (int i=0;i<8;i++) a[i]=0.f;
  for (int p=s; p<e; ++p) {
    const h8 v = *(const h8*)(h + (size_t)col[p]*200 + c*8);
    #pragma unroll
    for (int i=0;i<8;i++) a[i] += (float)v[i];
  }
  h8 o;
  #pragma unroll
  for (int i=0;i<8;i++) o[i] = (_Float16)a[i];
  *(h8*)(out + (size_t)n*200 + c*8) = o;
}

// ---------------- MFMA fused GRU ----------------
// Block: 512 thr (8 waves), 32 rows. A (hagg,h) staged in LDS once (K padded to 224).
// Wave (rsub = w&1, q = w>>1): rows rsub*16..+16, j-tiles {q, q+4, q+8, q+12}.
// acc[t][g]: g 0..2 = gi gates (A=hagg), 3..5 = gh gates (A=h).
__global__ __launch_bounds__(512) void gru_mfma(
    const _Float16* __restrict__ hagg, const _Float16* __restrict__ h,
    const _Float16* __restrict__ Bp,
    const float* __restrict__ bih, const float* __restrict__ bhh,
    _Float16* __restrict__ hnew) {
  __shared__ _Float16 As[2][32][232];   // stride 232: 2-way (free) bank pattern
  const int tid = threadIdx.x;
  const int bm = blockIdx.x * 32;

  for (int idx = tid; idx < 1792; idx += 512) {   // 2*32*28 chunks of 8 fp16
    int m_ = idx / 896; int rem = idx - m_*896;
    int row = rem / 28; int kc = rem - row*28;
    h8 v;
    #pragma unroll
    for (int i=0;i<8;i++) v[i] = (_Float16)0.f;
    if (kc < 25) {
      const _Float16* src = m_ ? h : hagg;
      v = *(const h8*)(src + (size_t)(bm+row)*200 + kc*8);
    }
    *(h8*)&As[m_][row][kc*8] = v;
  }
  __syncthreads();

  const int lane = tid & 63;
  const int w = tid >> 6;
  const int rsub = w & 1;
  const int q = w >> 1;
  const int lrow = lane & 15;
  const int kg = lane >> 4;

  f4 acc[4][6];
  #pragma unroll
  for (int t=0;t<4;t++)
    #pragma unroll
    for (int g=0;g<6;g++) { acc[t][g][0]=0.f; acc[t][g][1]=0.f; acc[t][g][2]=0.f; acc[t][g][3]=0.f; }

  #pragma unroll
  for (int s=0; s<7; s++) {
    const h8 aA = *(const h8*)&As[0][rsub*16 + lrow][s*32 + kg*8];
    const h8 aH = *(const h8*)&As[1][rsub*16 + lrow][s*32 + kg*8];
    #pragma unroll
    for (int t=0;t<4;t++) {
      const int jt = q + 4*t;
      if (jt < 13) {
        const int jj = jt*16 + lrow;
        #pragma unroll
        for (int g=0; g<6; g++) {
          const h8 b = *(const h8*)(Bp + (((size_t)(g*7+s)*208 + jj)*32 + kg*8));
          acc[t][g] = __builtin_amdgcn_mfma_f32_16x16x32_f16((g<3)?aA:aH, b, acc[t][g], 0,0,0);
        }
      }
    }
  }

  // epilogue: C layout col=lane&15, row=(lane>>4)*4+reg
  #pragma unroll
  for (int t=0;t<4;t++) {
    const int jt = q + 4*t;
    const int j = jt*16 + lrow;
    if (jt < 13 && j < 200) {
      const float bri = bih[j],      brh = bhh[j];
      const float bzi = bih[200+j],  bzh = bhh[200+j];
      const float bni = bih[400+j],  bnh = bhh[400+j];
      #pragma unroll
      for (int r=0;r<4;r++) {
        const int lr = rsub*16 + kg*4 + r;
        const float rr = 1.f/(1.f+expf(-(acc[t][0][r]+bri + acc[t][3][r]+brh)));
        const float zz = 1.f/(1.f+expf(-(acc[t][1][r]+bzi + acc[t][4][r]+bzh)));
        const float nn = tanhf(acc[t][2][r]+bni + rr*(acc[t][5][r]+bnh));
        const float hv = (float)As[1][lr][j];
        hnew[(size_t)(bm+lr)*200 + j] = (_Float16)((1.f-zz)*nn + zz*hv);
      }
    }
  }
}

// ---------------- head ----------------
__global__ __launch_bounds__(256) void conv1_kernel(const _Float16* __restrict__ hid,
        const float* __restrict__ x, const float* __restrict__ w, const float* __restrict__ bias,
        int LIN, float* __restrict__ out) {
  __shared__ float sm[NPG][66];
  int b = blockIdx.y;
  int t0 = blockIdx.x * 64;
  for (int idx = threadIdx.x; idx < NPG*66; idx += 256) {
    int p = idx / 66, c = idx - p*66;
    int l = t0 - 1 + c;
    float v = 0.f;
    if (l >= 0 && l < LIN) {
      long node = (long)b*NPG + p;
      v = (l < OUT) ? (float)hid[node*OUT + l] : x[node*EMB + (l-OUT)];
    }
    sm[p][c] = v;
  }
  __syncthreads();
  int tl = threadIdx.x & 63;
  int og = threadIdx.x >> 6;
  int t = t0 + tl;
  if (t >= LIN) return;
  for (int o = og; o < 50; o += 4) {
    float acc = bias[o];
    const float* wr = w + o*NPG*3;
    for (int p = 0; p < NPG; ++p) {
      acc += wr[p*3+0]*sm[p][tl] + wr[p*3+1]*sm[p][tl+1] + wr[p*3+2]*sm[p][tl+2];
    }
    out[((long)b*50 + o)*LIN + t] = acc;
  }
}

__global__ void bn_stats(const float* __restrict__ v, int C, int L, float* __restrict__ sums) {
  int c = blockIdx.x;
  int bs = blockIdx.y * 32;
  float s = 0.f, s2 = 0.f;
  for (int idx = threadIdx.x; idx < 32*L; idx += 256) {
    int b = bs + idx / L, t = idx - (idx/L)*L;
    float val = v[((long)b*C + c)*L + t];
    s += val; s2 += val*val;
  }
  __shared__ float rs[256], rq[256];
  rs[threadIdx.x]=s; rq[threadIdx.x]=s2; __syncthreads();
  for (int d=128; d>0; d>>=1){
    if (threadIdx.x<d){ rs[threadIdx.x]+=rs[threadIdx.x+d]; rq[threadIdx.x]+=rq[threadIdx.x+d]; }
    __syncthreads();
  }
  if (threadIdx.x==0){ atomicAdd(&sums[2*c], rs[0]); atomicAdd(&sums[2*c+1], rq[0]); }
}

__global__ void bn_finalize(const float* __restrict__ sums, const float* __restrict__ g,
        const float* __restrict__ b, int C, float inv_n, float* __restrict__ scale, float* __restrict__ shift) {
  int c = threadIdx.x;
  if (c < C) {
    float mean = sums[2*c]*inv_n;
    float var = sums[2*c+1]*inv_n - mean*mean;
    float sc = g[c]*rsqrtf(var + 1e-5f);
    scale[c] = sc;
    shift[c] = b[c] - mean*sc;
  }
}

__global__ void bn_act_pool(const float* __restrict__ v, const float* __restrict__ sc,
      const float* __restrict__ sh, int C, int Lin, int Lout, int K, int do_relu, float* __restrict__ out) {
  int idx = blockIdx.x*256 + threadIdx.x;
  int total = BATCH*C*Lout;
  if (idx>=total) return;
  int t = idx % Lout; int r = idx / Lout; int c = r % C; int b = r / C;
  const float* src = v + ((long)(b*C + c))*Lin + 2*t;
  float m = -3.4e38f;
  for (int k=0;k<K;k++){
    float u = src[k]*sc[c] + sh[c];
    if (do_relu) u = (u>=0.f)? u : 0.01f*u;
    m = fmaxf(m,u);
  }
  out[idx] = m;
}

__global__ __launch_bounds__(256) void conv2_kernel(const float* __restrict__ in,
        const float* __restrict__ w, const float* __restrict__ b2, int Lm, float* __restrict__ out) {
  __shared__ float sw[1000];
  __shared__ float sin[50*150];
  int b = blockIdx.x;
  for (int i=threadIdx.x;i<1000;i+=256) sw[i]=w[i];
  for (int i=threadIdx.x;i<50*Lm;i+=256) sin[i] = in[(long)b*50*Lm + i];
  __syncthreads();
  int Lo = Lm + 2;
  for (int idx=threadIdx.x; idx<20*Lo; idx+=256) {
    int c = idx / Lo, t = idx - c*Lo;
    float acc = b2[c];
    if (t>=1 && t<=Lm) {
      const float* sp = sin + (t-1);
      const float* wp = sw + c*50;
      for (int i=0;i<50;i++) acc += wp[i]*sp[i*Lm];
    }
    out[(long)b*20*Lo + idx] = acc;
  }
}

__global__ void final_kernel(const float* __restrict__ Zf, const float* __restrict__ Yf,
        const float* __restrict__ fc1w, const float* __restrict__ fc1b,
        const float* __restrict__ fc2w, const float* __restrict__ fc2b, float* __restrict__ out) {
  int b = blockIdx.x;
  float s1=0.f, s2=0.f;
  for (int i=threadIdx.x;i<1520;i+=256) s1 += Zf[(long)b*1520+i]*fc1w[i];
  for (int i=threadIdx.x;i<1000;i+=256) s2 += Yf[(long)b*1000+i]*fc2w[i];
  __shared__ float r1[256], r2[256];
  r1[threadIdx.x]=s1; r2[threadIdx.x]=s2; __syncthreads();
  for (int d=128; d>0; d>>=1){
    if (threadIdx.x<d){ r1[threadIdx.x]+=r1[threadIdx.x+d]; r2[threadIdx.x]+=r2[threadIdx.x+d]; }
    __syncthreads();
  }
  if (threadIdx.x==0){
    float res = (r1[0]+fc1b[0])*(r2[0]+fc2b[0]);
    out[b] = 1.f/(1.f+expf(-res));
  }
}

// ---------------- launch ----------------
extern "C" void kernel_launch(void* const* d_in, const int* in_sizes, int n_in,
                              void* d_out, int out_size, void* d_ws, size_t ws_size,
                              hipStream_t stream) {
  const float* x    = (const float*)d_in[0];
  const int*   ei   = (const int*)d_in[1];
  const float* ggcw = (const float*)d_in[2];
  const float* wih  = (const float*)d_in[3];
  const float* whh  = (const float*)d_in[4];
  const float* bih  = (const float*)d_in[5];
  const float* bhh  = (const float*)d_in[6];
  const float* c1w  = (const float*)d_in[7];
  const float* c1b  = (const float*)d_in[8];
  const float* bn1g = (const float*)d_in[9];
  const float* bn1b = (const float*)d_in[10];
  const float* c2w  = (const float*)d_in[11];
  const float* c2b  = (const float*)d_in[12];
  const float* bn2g = (const float*)d_in[13];
  const float* bn2b = (const float*)d_in[14];
  const float* fc1w = (const float*)d_in[15];
  const float* fc1b = (const float*)d_in[16];
  const float* fc2w = (const float*)d_in[17];
  const float* fc2b = (const float*)d_in[18];
  float* out = (float*)d_out;

  char* ws = (char*)d_ws;
  size_t HS = (size_t)NN*OUT*2;                       // fp16 h buffer: 41,984,000 B
  _Float16* h0 = (_Float16*)ws;
  _Float16* h1 = (_Float16*)(ws + HS);
  _Float16* h2 = (_Float16*)(ws + 2*HS);
  char* aux = ws + 3*HS;
  float*    Wf = (float*)aux;    aux += (size_t)6*200*600*4;        // 2.88 MB
  _Float16* Bp = (_Float16*)aux; aux += (size_t)6*6*7*208*32*2;     // 3.35 MB
  int* rowptr = (int*)aux;       aux += (size_t)(NN+16)*4;
  int* cursor = (int*)aux;       aux += (size_t)NN*4;
  int* col    = (int*)aux;       aux += (size_t)NE*4;
  float* sums = (float*)aux;     aux += 128*4;
  float* sc   = (float*)aux;     aux += 64*4;
  float* sh   = (float*)aux;     aux += 64*4;
  // head scratch (fp32), placed after GGC data
  float* z_c1  = (float*)aux;
  float* y_c1  = z_c1  + (size_t)512*50*301;
  float* z_mp1 = y_c1  + (size_t)512*50*200;
  float* y_mp1 = z_mp1 + (size_t)512*50*150;
  float* z_c2  = y_mp1 + (size_t)512*50*99;
  float* y_c2  = z_c2  + (size_t)512*20*152;
  float* z_mp2 = y_c2  + (size_t)512*20*101;
  float* y_mp2 = z_mp2 + (size_t)512*1520;

  // precompute
  pad16<<<NN*OUT/256, 256, 0, stream>>>(x, h0);
  fuse_w_kernel<<<(6*200*600+255)/256, 256, 0, stream>>>(ggcw, wih, Wf);
  pack_b<<<6*6*7*208*32/256, 256, 0, stream>>>(Wf, whh, Bp);
  // CSR
  zero_i32<<<(NN+255)/256, 256, 0, stream>>>(cursor, NN);
  count_deg<<<NE/256, 256, 0, stream>>>(ei, cursor);
  scan_kernel<<<1, 1024, 0, stream>>>(cursor, rowptr);
  copy_i32<<<(NN+255)/256, 256, 0, stream>>>(rowptr, cursor, NN);
  fill_csr<<<NE/256, 256, 0, stream>>>(ei, cursor, col);

  // GGC layers
  _Float16* cur = h0; _Float16* other = h2;
  for (int i=0;i<LAYERS;i++){
    gather16<<<NN*25/256, 256, 0, stream>>>(cur, rowptr, col, h1);
    gru_mfma<<<NN/32, 512, 0, stream>>>(h1, cur, Bp + (size_t)i*6*7*208*32,
                                        bih, bhh, other);
    _Float16* t = cur; cur = other; other = t;
  }
  // cur == h0 (final hidden, fp16)

  // head
  conv1_kernel<<<dim3(5, BATCH), 256, 0, stream>>>(cur, x, c1w, c1b, 301, z_c1);
  conv1_kernel<<<dim3(4, BATCH), 256, 0, stream>>>(cur, x, c1w, c1b, 200, y_c1);

  zero_f32<<<1, 128, 0, stream>>>(sums, 128);
  bn_stats<<<dim3(50,16), 256, 0, stream>>>(z_c1, 50, 301, sums);
  bn_finalize<<<1, 64, 0, stream>>>(sums, bn1g, bn1b, 50, 1.f/(512.f*301.f), sc, sh);
  bn_act_pool<<<(512*50*150+255)/256, 256, 0, stream>>>(z_c1, sc, sh, 50, 301, 150, 3, 1, z_mp1);

  zero_f32<<<1, 128, 0, stream>>>(sums, 128);
  bn_stats<<<dim3(50,16), 256, 0, stream>>>(y_c1, 50, 200, sums);
  bn_finalize<<<1, 64, 0, stream>>>(sums, bn1g, bn1b, 50, 1.f/(512.f*200.f), sc, sh);
  bn_act_pool<<<(512*50*99+255)/256, 256, 0, stream>>>(y_c1, sc, sh, 50, 200, 99, 3, 1, y_mp1);

  conv2_kernel<<<BATCH, 256, 0, stream>>>(z_mp1, c2w, c2b, 150, z_c2);
  conv2_kernel<<<BATCH, 256, 0, stream>>>(y_mp1, c2w, c2b, 99, y_c2);

  zero_f32<<<1, 128, 0, stream>>>(sums, 128);
  bn_stats<<<dim3(20,16), 256, 0, stream>>>(z_c2, 20, 152, sums);
  bn_finalize<<<1, 64, 0, stream>>>(sums, bn2g, bn2b, 20, 1.f/(512.f*152.f), sc, sh);
  bn_act_pool<<<(512*20*76+255)/256, 256, 0, stream>>>(z_c2, sc, sh, 20, 152, 76, 2, 0, z_mp2);

  zero_f32<<<1, 128, 0, stream>>>(sums, 128);
  bn_stats<<<dim3(20,16), 256, 0, stream>>>(y_c2, 20, 101, sums);
  bn_finalize<<<1, 64, 0, stream>>>(sums, bn2g, bn2b, 20, 1.f/(512.f*101.f), sc, sh);
  bn_act_pool<<<(512*20*50+255)/256, 256, 0, stream>>>(y_c2, sc, sh, 20, 101, 50, 2, 0, y_mp2);

  final_kernel<<<BATCH, 256, 0, stream>>>(z_mp2, y_mp2, fc1w, fc1b, fc2w, fc2b, out);
}

// Round 3
// 2576.509 us; speedup vs baseline: 9.3963x; 1.5002x over previous
//
#include <hip/hip_runtime.h>
#include <math.h>

#define NN 104960      // nodes
#define OUT 200
#define EMB 101
#define NPG 205
#define BATCH 512
#define NE 629760      // edges
#define LAYERS 6

typedef _Float16 h8 __attribute__((ext_vector_type(8)));
typedef float f4 __attribute__((ext_vector_type(4)));

// ---------------- utility kernels ----------------
__global__ void zero_i32(int* p, int n){ int i=blockIdx.x*256+threadIdx.x; if(i<n) p[i]=0; }
__global__ void zero_f32(float* p, int n){ int i=blockIdx.x*blockDim.x+threadIdx.x; if(i<n) p[i]=0.f; }
__global__ void copy_i32(const int* __restrict__ a, int* __restrict__ b, int n){
  int i=blockIdx.x*256+threadIdx.x; if(i<n) b[i]=a[i];
}

// h[N,200] fp16 = pad(x[N,101])
__global__ void pad16(const float* __restrict__ x, _Float16* __restrict__ h) {
  int idx = blockIdx.x*256 + threadIdx.x;
  if (idx >= NN*OUT) return;
  int n = idx / OUT, j = idx - n*OUT;
  h[idx] = (j < EMB) ? (_Float16)x[n*EMB + j] : (_Float16)0.f;
}

// Wf[i][k][o] = sum_j ggc_w[i][k][j] * wih[o][j]   (i<6, k<200, o<600)  fp32
__global__ void fuse_w_kernel(const float* __restrict__ ggc_w, const float* __restrict__ wih,
                              float* __restrict__ Wf) {
  long idx = (long)blockIdx.x*256 + threadIdx.x;
  if (idx >= 6L*200*600) return;
  int o = (int)(idx % 600); long r = idx / 600; int k = (int)(r % 200); int i = (int)(r / 200);
  const float* wr = ggc_w + ((long)i*200 + k)*200;
  const float* vr = wih + (long)o*200;
  float acc = 0.f;
  for (int j=0;j<200;j++) acc += wr[j]*vr[j];
  Wf[idx] = acc;
}

// Bp[layer][gate][s][j(208)][kk(32)] fp16, fragment-order B for MFMA.
__global__ void pack_b(const float* __restrict__ Wf, const float* __restrict__ whh,
                       _Float16* __restrict__ Bp) {
  size_t idx = (size_t)blockIdx.x*256 + threadIdx.x;
  if (idx >= 6UL*6*7*208*32) return;
  int kk = (int)(idx & 31); size_t r = idx >> 5;
  int j = (int)(r % 208); r /= 208;
  int s = (int)(r % 7);   r /= 7;
  int g = (int)(r % 6);   int l = (int)(r / 6);
  int k = s*32 + kk;
  float v = 0.f;
  if (k < 200 && j < 200) {
    v = (g < 3) ? Wf[(size_t)l*120000 + (size_t)k*600 + g*200 + j]
                : whh[((size_t)(g-3)*200 + j)*200 + k];
  }
  Bp[idx] = (_Float16)v;
}

// conv1 weights -> fragment order Wp[s(21)][o(64)][kk(32)] fp16
// K ordering: k = kc*224 + p (each kc block padded 205->224)
__global__ void pack_w1(const float* __restrict__ w, _Float16* __restrict__ Wp) {
  int idx = blockIdx.x*256 + threadIdx.x;   // 21*64*32 = 43008
  if (idx >= 21*64*32) return;
  int kk = idx & 31; int r = idx >> 5;
  int o = r & 63; int s = r >> 6;
  int kc = s/7, p = (s%7)*32 + kk;
  float v = 0.f;
  if (o < 50 && p < 205) v = w[o*615 + p*3 + kc];
  Wp[idx] = (_Float16)v;
}

// ---------------- CSR build ----------------
__global__ void count_deg(const int* __restrict__ ei, int* __restrict__ cnt) {
  int e = blockIdx.x*256+threadIdx.x;
  if (e < NE) atomicAdd(&cnt[ei[NE + e]], 1);
}

__global__ __launch_bounds__(1024) void scan_kernel(const int* __restrict__ cnt, int* __restrict__ rowptr) {
  __shared__ int sdata[1024];
  __shared__ int s_off;
  int tid = threadIdx.x;
  if (tid==0) s_off = 0;
  __syncthreads();
  for (int base=0; base<NN; base+=1024) {
    int i = base + tid;
    int v = (i<NN)? cnt[i] : 0;
    sdata[tid] = v;
    __syncthreads();
    for (int d=1; d<1024; d<<=1) {
      int t = (tid>=d)? sdata[tid-d] : 0;
      __syncthreads();
      sdata[tid] += t;
      __syncthreads();
    }
    if (i<NN) rowptr[i] = s_off + sdata[tid] - v;
    __syncthreads();
    if (tid==1023) s_off += sdata[1023];
    __syncthreads();
  }
  if (tid==0) rowptr[NN] = s_off;
}

__global__ void fill_csr(const int* __restrict__ ei, int* __restrict__ cursor, int* __restrict__ col) {
  int e = blockIdx.x*256+threadIdx.x;
  if (e < NE) {
    int dst = ei[NE+e], src = ei[e];
    int pos = atomicAdd(&cursor[dst], 1);
    col[pos] = src;
  }
}

// hagg[n,:] += h[col,:] ; thread = (node, 8-elem chunk), 25 chunks/node
__global__ void gather16(const _Float16* __restrict__ h, const int* __restrict__ rowptr,
                         const int* __restrict__ col, _Float16* __restrict__ out) {
  int idx = blockIdx.x*256 + threadIdx.x;
  if (idx >= NN*25) return;
  int n = idx / 25, c = idx - n*25;
  int s = rowptr[n], e = rowptr[n+1];
  float a[8];
  #pragma unroll
  for (int i=0;i<8;i++) a[i]=0.f;
  for (int p=s; p<e; ++p) {
    const h8 v = *(const h8*)(h + (size_t)col[p]*200 + c*8);
    #pragma unroll
    for (int i=0;i<8;i++) a[i] += (float)v[i];
  }
  h8 o;
  #pragma unroll
  for (int i=0;i<8;i++) o[i] = (_Float16)a[i];
  *(h8*)(out + (size_t)n*200 + c*8) = o;
}

// ---------------- MFMA fused GRU ----------------
__global__ __launch_bounds__(512) void gru_mfma(
    const _Float16* __restrict__ hagg, const _Float16* __restrict__ h,
    const _Float16* __restrict__ Bp,
    const float* __restrict__ bih, const float* __restrict__ bhh,
    _Float16* __restrict__ hnew) {
  __shared__ _Float16 As[2][32][232];
  const int tid = threadIdx.x;
  const int bm = blockIdx.x * 32;

  for (int idx = tid; idx < 1792; idx += 512) {
    int m_ = idx / 896; int rem = idx - m_*896;
    int row = rem / 28; int kc = rem - row*28;
    h8 v;
    #pragma unroll
    for (int i=0;i<8;i++) v[i] = (_Float16)0.f;
    if (kc < 25) {
      const _Float16* src = m_ ? h : hagg;
      v = *(const h8*)(src + (size_t)(bm+row)*200 + kc*8);
    }
    *(h8*)&As[m_][row][kc*8] = v;
  }
  __syncthreads();

  const int lane = tid & 63;
  const int w = tid >> 6;
  const int rsub = w & 1;
  const int q = w >> 1;
  const int lrow = lane & 15;
  const int kg = lane >> 4;

  f4 acc[4][6];
  #pragma unroll
  for (int t=0;t<4;t++)
    #pragma unroll
    for (int g=0;g<6;g++) { acc[t][g][0]=0.f; acc[t][g][1]=0.f; acc[t][g][2]=0.f; acc[t][g][3]=0.f; }

  #pragma unroll
  for (int s=0; s<7; s++) {
    const h8 aA = *(const h8*)&As[0][rsub*16 + lrow][s*32 + kg*8];
    const h8 aH = *(const h8*)&As[1][rsub*16 + lrow][s*32 + kg*8];
    #pragma unroll
    for (int t=0;t<4;t++) {
      const int jt = q + 4*t;
      if (jt < 13) {
        const int jj = jt*16 + lrow;
        #pragma unroll
        for (int g=0; g<6; g++) {
          const h8 b = *(const h8*)(Bp + (((size_t)(g*7+s)*208 + jj)*32 + kg*8));
          acc[t][g] = __builtin_amdgcn_mfma_f32_16x16x32_f16((g<3)?aA:aH, b, acc[t][g], 0,0,0);
        }
      }
    }
  }

  #pragma unroll
  for (int t=0;t<4;t++) {
    const int jt = q + 4*t;
    const int j = jt*16 + lrow;
    if (jt < 13 && j < 200) {
      const float bri = bih[j],      brh = bhh[j];
      const float bzi = bih[200+j],  bzh = bhh[200+j];
      const float bni = bih[400+j],  bnh = bhh[400+j];
      #pragma unroll
      for (int r=0;r<4;r++) {
        const int lr = rsub*16 + kg*4 + r;
        const float rr = 1.f/(1.f+expf(-(acc[t][0][r]+bri + acc[t][3][r]+brh)));
        const float zz = 1.f/(1.f+expf(-(acc[t][1][r]+bzi + acc[t][4][r]+bzh)));
        const float nn = tanhf(acc[t][2][r]+bni + rr*(acc[t][5][r]+bnh));
        const float hv = (float)As[1][lr][j];
        hnew[(size_t)(bm+lr)*200 + j] = (_Float16)((1.f-zz)*nn + zz*hv);
      }
    }
  }
}

// ---------------- head ----------------
// Xt[b][l(304)][p(224)] fp16: l<200 from hid, 200<=l<301 from x, else 0; p>=205 zero.
__global__ __launch_bounds__(256) void build_xt(const _Float16* __restrict__ hid,
        const float* __restrict__ x, _Float16* __restrict__ Xt) {
  __shared__ _Float16 T[32][34];
  int pt = blockIdx.x*32, lt = blockIdx.y*32, b = blockIdx.z;
  int lo = threadIdx.x & 31;
  int po = threadIdx.x >> 5;
  #pragma unroll
  for (int q=0;q<4;q++) {
    int p = pt + po + q*8;
    int l = lt + lo;
    _Float16 v = (_Float16)0.f;
    if (p < 205 && l < 301) {
      size_t node = (size_t)b*205 + p;
      v = (l < 200) ? hid[node*200 + l] : (_Float16)x[node*101 + (l-200)];
    }
    T[po + q*8][lo] = v;
  }
  __syncthreads();
  #pragma unroll
  for (int q=0;q<4;q++) {
    int l = lt + po + q*8;
    int p = pt + lo;
    if (l < 304)
      Xt[((size_t)b*304 + l)*224 + p] = T[lo][po + q*8];
  }
}

// out[b,o,t] = bias[o] + sum_{kc,p} W[o,p,kc] * Xt[b][t+kc-1][p]
// wave = one 16-t subtile; 21 K-slices x 4 o-tiles of 16x16x32 MFMA.
__global__ __launch_bounds__(256) void conv1_mfma(const _Float16* __restrict__ Xt,
        const _Float16* __restrict__ Wp, const float* __restrict__ bias,
        int LIN, float* __restrict__ out) {
  int b = blockIdx.y;
  int t0 = blockIdx.x * 64;
  int lane = threadIdx.x & 63;
  int tt = threadIdx.x >> 6;
  int j = lane & 15;
  int kg = lane >> 4;
  int t = t0 + tt*16 + j;
  f4 acc[4];
  #pragma unroll
  for (int a=0;a<4;a++) { acc[a][0]=0.f; acc[a][1]=0.f; acc[a][2]=0.f; acc[a][3]=0.f; }
  const _Float16* xb = Xt + (size_t)b*304*224;
  #pragma unroll
  for (int s=0; s<21; s++) {
    const int kc = s/7;
    const int p0 = (s - kc*7)*32 + kg*8;
    const int tp = t + kc - 1;
    h8 bfrag = {0,0,0,0,0,0,0,0};
    if (tp >= 0 && tp < LIN) bfrag = *(const h8*)(xb + (size_t)tp*224 + p0);
    #pragma unroll
    for (int a=0;a<4;a++) {
      const h8 afrag = *(const h8*)(Wp + ((size_t)(s*64 + a*16 + j)*32 + kg*8));
      acc[a] = __builtin_amdgcn_mfma_f32_16x16x32_f16(afrag, bfrag, acc[a], 0,0,0);
    }
  }
  if (t < LIN) {
    #pragma unroll
    for (int a=0;a<4;a++) {
      #pragma unroll
      for (int r=0;r<4;r++) {
        int o = a*16 + kg*4 + r;
        if (o < 50) out[((size_t)b*50 + o)*LIN + t] = acc[a][r] + bias[o];
      }
    }
  }
}

__global__ void bn_stats(const float* __restrict__ v, int C, int L, float* __restrict__ sums) {
  int c = blockIdx.x;
  int bs = blockIdx.y * 32;
  float s = 0.f, s2 = 0.f;
  for (int idx = threadIdx.x; idx < 32*L; idx += 256) {
    int b = bs + idx / L, t = idx - (idx/L)*L;
    float val = v[((long)b*C + c)*L + t];
    s += val; s2 += val*val;
  }
  __shared__ float rs[256], rq[256];
  rs[threadIdx.x]=s; rq[threadIdx.x]=s2; __syncthreads();
  for (int d=128; d>0; d>>=1){
    if (threadIdx.x<d){ rs[threadIdx.x]+=rs[threadIdx.x+d]; rq[threadIdx.x]+=rq[threadIdx.x+d]; }
    __syncthreads();
  }
  if (threadIdx.x==0){ atomicAdd(&sums[2*c], rs[0]); atomicAdd(&sums[2*c+1], rq[0]); }
}

__global__ void bn_finalize(const float* __restrict__ sums, const float* __restrict__ g,
        const float* __restrict__ b, int C, float inv_n, float* __restrict__ scale, float* __restrict__ shift) {
  int c = threadIdx.x;
  if (c < C) {
    float mean = sums[2*c]*inv_n;
    float var = sums[2*c+1]*inv_n - mean*mean;
    float sc = g[c]*rsqrtf(var + 1e-5f);
    scale[c] = sc;
    shift[c] = b[c] - mean*sc;
  }
}

__global__ void bn_act_pool(const float* __restrict__ v, const float* __restrict__ sc,
      const float* __restrict__ sh, int C, int Lin, int Lout, int K, int do_relu, float* __restrict__ out) {
  int idx = blockIdx.x*256 + threadIdx.x;
  int total = BATCH*C*Lout;
  if (idx>=total) return;
  int t = idx % Lout; int r = idx / Lout; int c = r % C; int b = r / C;
  const float* src = v + ((long)(b*C + c))*Lin + 2*t;
  float m = -3.4e38f;
  for (int k=0;k<K;k++){
    float u = src[k]*sc[c] + sh[c];
    if (do_relu) u = (u>=0.f)? u : 0.01f*u;
    m = fmaxf(m,u);
  }
  out[idx] = m;
}

__global__ __launch_bounds__(256) void conv2_kernel(const float* __restrict__ in,
        const float* __restrict__ w, const float* __restrict__ b2, int Lm, float* __restrict__ out) {
  __shared__ float sw[1000];
  __shared__ float sin[50*150];
  int b = blockIdx.x;
  for (int i=threadIdx.x;i<1000;i+=256) sw[i]=w[i];
  for (int i=threadIdx.x;i<50*Lm;i+=256) sin[i] = in[(long)b*50*Lm + i];
  __syncthreads();
  int Lo = Lm + 2;
  for (int idx=threadIdx.x; idx<20*Lo; idx+=256) {
    int c = idx / Lo, t = idx - c*Lo;
    float acc = b2[c];
    if (t>=1 && t<=Lm) {
      const float* sp = sin + (t-1);
      const float* wp = sw + c*50;
      for (int i=0;i<50;i++) acc += wp[i]*sp[i*Lm];
    }
    out[(long)b*20*Lo + idx] = acc;
  }
}

__global__ void final_kernel(const float* __restrict__ Zf, const float* __restrict__ Yf,
        const float* __restrict__ fc1w, const float* __restrict__ fc1b,
        const float* __restrict__ fc2w, const float* __restrict__ fc2b, float* __restrict__ out) {
  int b = blockIdx.x;
  float s1=0.f, s2=0.f;
  for (int i=threadIdx.x;i<1520;i+=256) s1 += Zf[(long)b*1520+i]*fc1w[i];
  for (int i=threadIdx.x;i<1000;i+=256) s2 += Yf[(long)b*1000+i]*fc2w[i];
  __shared__ float r1[256], r2[256];
  r1[threadIdx.x]=s1; r2[threadIdx.x]=s2; __syncthreads();
  for (int d=128; d>0; d>>=1){
    if (threadIdx.x<d){ r1[threadIdx.x]+=r1[threadIdx.x+d]; r2[threadIdx.x]+=r2[threadIdx.x+d]; }
    __syncthreads();
  }
  if (threadIdx.x==0){
    float res = (r1[0]+fc1b[0])*(r2[0]+fc2b[0]);
    out[b] = 1.f/(1.f+expf(-res));
  }
}

// ---------------- launch ----------------
extern "C" void kernel_launch(void* const* d_in, const int* in_sizes, int n_in,
                              void* d_out, int out_size, void* d_ws, size_t ws_size,
                              hipStream_t stream) {
  const float* x    = (const float*)d_in[0];
  const int*   ei   = (const int*)d_in[1];
  const float* ggcw = (const float*)d_in[2];
  const float* wih  = (const float*)d_in[3];
  const float* whh  = (const float*)d_in[4];
  const float* bih  = (const float*)d_in[5];
  const float* bhh  = (const float*)d_in[6];
  const float* c1w  = (const float*)d_in[7];
  const float* c1b  = (const float*)d_in[8];
  const float* bn1g = (const float*)d_in[9];
  const float* bn1b = (const float*)d_in[10];
  const float* c2w  = (const float*)d_in[11];
  const float* c2b  = (const float*)d_in[12];
  const float* bn2g = (const float*)d_in[13];
  const float* bn2b = (const float*)d_in[14];
  const float* fc1w = (const float*)d_in[15];
  const float* fc1b = (const float*)d_in[16];
  const float* fc2w = (const float*)d_in[17];
  const float* fc2b = (const float*)d_in[18];
  float* out = (float*)d_out;

  char* ws = (char*)d_ws;
  size_t HS = (size_t)NN*OUT*2;                       // 41,984,000 B per h buffer
  _Float16* h0 = (_Float16*)ws;
  _Float16* h1 = (_Float16*)(ws + HS);
  _Float16* h2 = (_Float16*)(ws + 2*HS);
  _Float16* Xt = h1;                                  // overlay: 512*304*224*2 = 69.7 MB < 84 MB
  char* aux = ws + 3*HS;
  float*    Wf = (float*)aux;    aux += (size_t)6*200*600*4;
  _Float16* Bp = (_Float16*)aux; aux += (size_t)6*6*7*208*32*2;
  _Float16* Wp1 = (_Float16*)aux; aux += (size_t)21*64*32*2;
  int* rowptr = (int*)aux;       aux += (size_t)(NN+16)*4;
  int* cursor = (int*)aux;       aux += (size_t)NN*4;
  int* col    = (int*)aux;       aux += (size_t)NE*4;
  float* sums = (float*)aux;     aux += 128*4;
  float* sc   = (float*)aux;     aux += 64*4;
  float* sh   = (float*)aux;     aux += 64*4;
  float* z_c1  = (float*)aux;
  float* y_c1  = z_c1  + (size_t)512*50*301;
  float* z_mp1 = y_c1  + (size_t)512*50*200;
  float* y_mp1 = z_mp1 + (size_t)512*50*150;
  float* z_c2  = y_mp1 + (size_t)512*50*99;
  float* y_c2  = z_c2  + (size_t)512*20*152;
  float* z_mp2 = y_c2  + (size_t)512*20*101;
  float* y_mp2 = z_mp2 + (size_t)512*1520;

  // precompute
  pad16<<<NN*OUT/256, 256, 0, stream>>>(x, h0);
  fuse_w_kernel<<<(6*200*600+255)/256, 256, 0, stream>>>(ggcw, wih, Wf);
  pack_b<<<6*6*7*208*32/256, 256, 0, stream>>>(Wf, whh, Bp);
  pack_w1<<<(21*64*32+255)/256, 256, 0, stream>>>(c1w, Wp1);
  // CSR
  zero_i32<<<(NN+255)/256, 256, 0, stream>>>(cursor, NN);
  count_deg<<<NE/256, 256, 0, stream>>>(ei, cursor);
  scan_kernel<<<1, 1024, 0, stream>>>(cursor, rowptr);
  copy_i32<<<(NN+255)/256, 256, 0, stream>>>(rowptr, cursor, NN);
  fill_csr<<<NE/256, 256, 0, stream>>>(ei, cursor, col);

  // GGC layers
  _Float16* cur = h0; _Float16* other = h2;
  for (int i=0;i<LAYERS;i++){
    gather16<<<NN*25/256, 256, 0, stream>>>(cur, rowptr, col, h1);
    gru_mfma<<<NN/32, 512, 0, stream>>>(h1, cur, Bp + (size_t)i*6*7*208*32,
                                        bih, bhh, other);
    _Float16* t = cur; cur = other; other = t;
  }
  // cur == h0 (final hidden, fp16); h1/h2 free -> Xt overlay

  // head
  build_xt<<<dim3(7, 10, BATCH), 256, 0, stream>>>(cur, x, Xt);
  conv1_mfma<<<dim3(5, BATCH), 256, 0, stream>>>(Xt, Wp1, c1b, 301, z_c1);
  conv1_mfma<<<dim3(4, BATCH), 256, 0, stream>>>(Xt, Wp1, c1b, 200, y_c1);

  zero_f32<<<1, 128, 0, stream>>>(sums, 128);
  bn_stats<<<dim3(50,16), 256, 0, stream>>>(z_c1, 50, 301, sums);
  bn_finalize<<<1, 64, 0, stream>>>(sums, bn1g, bn1b, 50, 1.f/(512.f*301.f), sc, sh);
  bn_act_pool<<<(512*50*150+255)/256, 256, 0, stream>>>(z_c1, sc, sh, 50, 301, 150, 3, 1, z_mp1);

  zero_f32<<<1, 128, 0, stream>>>(sums, 128);
  bn_stats<<<dim3(50,16), 256, 0, stream>>>(y_c1, 50, 200, sums);
  bn_finalize<<<1, 64, 0, stream>>>(sums, bn1g, bn1b, 50, 1.f/(512.f*200.f), sc, sh);
  bn_act_pool<<<(512*50*99+255)/256, 256, 0, stream>>>(y_c1, sc, sh, 50, 200, 99, 3, 1, y_mp1);

  conv2_kernel<<<BATCH, 256, 0, stream>>>(z_mp1, c2w, c2b, 150, z_c2);
  conv2_kernel<<<BATCH, 256, 0, stream>>>(y_mp1, c2w, c2b, 99, y_c2);

  zero_f32<<<1, 128, 0, stream>>>(sums, 128);
  bn_stats<<<dim3(20,16), 256, 0, stream>>>(z_c2, 20, 152, sums);
  bn_finalize<<<1, 64, 0, stream>>>(sums, bn2g, bn2b, 20, 1.f/(512.f*152.f), sc, sh);
  bn_act_pool<<<(512*20*76+255)/256, 256, 0, stream>>>(z_c2, sc, sh, 20, 152, 76, 2, 0, z_mp2);

  zero_f32<<<1, 128, 0, stream>>>(sums, 128);
  bn_stats<<<dim3(20,16), 256, 0, stream>>>(y_c2, 20, 101, sums);
  bn_finalize<<<1, 64, 0, stream>>>(sums, bn2g, bn2b, 20, 1.f/(512.f*101.f), sc, sh);
  bn_act_pool<<<(512*20*50+255)/256, 256, 0, stream>>>(y_c2, sc, sh, 20, 101, 50, 2, 0, y_mp2);

  final_kernel<<<BATCH, 256, 0, stream>>>(z_mp2, y_mp2, fc1w, fc1b, fc2w, fc2b, out);
}

// Round 4
// 1737.688 us; speedup vs baseline: 13.9321x; 1.4827x over previous
//
#include <hip/hip_runtime.h>
#include <math.h>

#define NN 104960      // nodes
#define OUT 200
#define EMB 101
#define NPG 205
#define BATCH 512
#define NE 629760      // edges
#define LAYERS 6

typedef _Float16 h8 __attribute__((ext_vector_type(8)));
typedef float f4 __attribute__((ext_vector_type(4)));
typedef float f16v __attribute__((ext_vector_type(16)));

// ---------------- utility kernels ----------------
__global__ void zero_i32(int* p, int n){ int i=blockIdx.x*256+threadIdx.x; if(i<n) p[i]=0; }
__global__ void zero_f32(float* p, int n){ int i=blockIdx.x*blockDim.x+threadIdx.x; if(i<n) p[i]=0.f; }
__global__ void copy_i32(const int* __restrict__ a, int* __restrict__ b, int n){
  int i=blockIdx.x*256+threadIdx.x; if(i<n) b[i]=a[i];
}

// h[N,200] fp16 = pad(x[N,101])
__global__ void pad16(const float* __restrict__ x, _Float16* __restrict__ h) {
  int idx = blockIdx.x*256 + threadIdx.x;
  if (idx >= NN*OUT) return;
  int n = idx / OUT, j = idx - n*OUT;
  h[idx] = (j < EMB) ? (_Float16)x[n*EMB + j] : (_Float16)0.f;
}

// Wf[i][k][o] = sum_j ggc_w[i][k][j] * wih[o][j]   (i<6, k<200, o<600)  fp32
__global__ void fuse_w_kernel(const float* __restrict__ ggc_w, const float* __restrict__ wih,
                              float* __restrict__ Wf) {
  long idx = (long)blockIdx.x*256 + threadIdx.x;
  if (idx >= 6L*200*600) return;
  int o = (int)(idx % 600); long r = idx / 600; int k = (int)(r % 200); int i = (int)(r / 200);
  const float* wr = ggc_w + ((long)i*200 + k)*200;
  const float* vr = wih + (long)o*200;
  float acc = 0.f;
  for (int j=0;j<200;j++) acc += wr[j]*vr[j];
  Wf[idx] = acc;
}

// Bp32[layer][gate][s(13)][j(224)][k(16)] fp16 — 32-wide fragment order for 32x32x16 MFMA.
// gate<3: B[k][g*200+j] = Wf_l[k*600+g*200+j]; gate>=3: = whh[((g-3)*200+j)*200+k]
__global__ void pack_b32(const float* __restrict__ Wf, const float* __restrict__ whh,
                         _Float16* __restrict__ Bp) {
  size_t idx = (size_t)blockIdx.x*256 + threadIdx.x;
  if (idx >= 6UL*6*13*224*16) return;
  int kk = (int)(idx & 15); size_t r = idx >> 4;
  int j = (int)(r % 224); r /= 224;
  int s = (int)(r % 13);  r /= 13;
  int g = (int)(r % 6);   int l = (int)(r / 6);
  int k = s*16 + kk;
  float v = 0.f;
  if (k < 200 && j < 200) {
    v = (g < 3) ? Wf[(size_t)l*120000 + (size_t)k*600 + g*200 + j]
                : whh[((size_t)(g-3)*200 + j)*200 + k];
  }
  Bp[idx] = (_Float16)v;
}

// conv1 weights -> fragment order Wp[s(21)][o(64)][kk(32)] fp16
__global__ void pack_w1(const float* __restrict__ w, _Float16* __restrict__ Wp) {
  int idx = blockIdx.x*256 + threadIdx.x;   // 21*64*32 = 43008
  if (idx >= 21*64*32) return;
  int kk = idx & 31; int r = idx >> 5;
  int o = r & 63; int s = r >> 6;
  int kc = s/7, p = (s%7)*32 + kk;
  float v = 0.f;
  if (o < 50 && p < 205) v = w[o*615 + p*3 + kc];
  Wp[idx] = (_Float16)v;
}

// ---------------- CSR build ----------------
__global__ void count_deg(const int* __restrict__ ei, int* __restrict__ cnt) {
  int e = blockIdx.x*256+threadIdx.x;
  if (e < NE) atomicAdd(&cnt[ei[NE + e]], 1);
}

__global__ __launch_bounds__(1024) void scan_kernel(const int* __restrict__ cnt, int* __restrict__ rowptr) {
  __shared__ int sdata[1024];
  __shared__ int s_off;
  int tid = threadIdx.x;
  if (tid==0) s_off = 0;
  __syncthreads();
  for (int base=0; base<NN; base+=1024) {
    int i = base + tid;
    int v = (i<NN)? cnt[i] : 0;
    sdata[tid] = v;
    __syncthreads();
    for (int d=1; d<1024; d<<=1) {
      int t = (tid>=d)? sdata[tid-d] : 0;
      __syncthreads();
      sdata[tid] += t;
      __syncthreads();
    }
    if (i<NN) rowptr[i] = s_off + sdata[tid] - v;
    __syncthreads();
    if (tid==1023) s_off += sdata[1023];
    __syncthreads();
  }
  if (tid==0) rowptr[NN] = s_off;
}

__global__ void fill_csr(const int* __restrict__ ei, int* __restrict__ cursor, int* __restrict__ col) {
  int e = blockIdx.x*256+threadIdx.x;
  if (e < NE) {
    int dst = ei[NE+e], src = ei[e];
    int pos = atomicAdd(&cursor[dst], 1);
    col[pos] = src;
  }
}

// hagg[n,:] += h[col,:] ; thread = (node, 8-elem chunk), 25 chunks/node
__global__ void gather16(const _Float16* __restrict__ h, const int* __restrict__ rowptr,
                         const int* __restrict__ col, _Float16* __restrict__ out) {
  int idx = blockIdx.x*256 + threadIdx.x;
  if (idx >= NN*25) return;
  int n = idx / 25, c = idx - n*25;
  int s = rowptr[n], e = rowptr[n+1];
  float a[8];
  #pragma unroll
  for (int i=0;i<8;i++) a[i]=0.f;
  for (int p=s; p<e; ++p) {
    const h8 v = *(const h8*)(h + (size_t)col[p]*200 + c*8);
    #pragma unroll
    for (int i=0;i<8;i++) a[i] += (float)v[i];
  }
  h8 o;
  #pragma unroll
  for (int i=0;i<8;i++) o[i] = (_Float16)a[i];
  *(h8*)(out + (size_t)n*200 + c*8) = o;
}

// ---------------- MFMA fused GRU (32x32x16) ----------------
// block 448 thr = 7 waves; M = 32 rows; wave w owns j-tile jt=w (32 cols), all 6 gates.
// acc[6] f32x16. A (hagg,h) in LDS, B fragments streamed from L2-hot Bp32.
__global__ __launch_bounds__(448) void gru_mfma2(
    const _Float16* __restrict__ hagg, const _Float16* __restrict__ h,
    const _Float16* __restrict__ Bp,
    const float* __restrict__ bih, const float* __restrict__ bhh,
    _Float16* __restrict__ hnew) {
  __shared__ _Float16 As[2][32][232];
  const int tid = threadIdx.x;
  const int bm = blockIdx.x * 32;

  for (int idx = tid; idx < 1600; idx += 448) {     // 2*32*25 h8 chunks
    int m_ = idx / 800; int rem = idx - m_*800;
    int row = rem / 25; int kc = rem - row*25;
    const _Float16* src = m_ ? h : hagg;
    *(h8*)&As[m_][row][kc*8] = *(const h8*)(src + (size_t)(bm+row)*200 + kc*8);
  }
  for (int idx = tid; idx < 256; idx += 448) {      // zero pad k = 200..231
    int m_ = idx / 128; int rem = idx - m_*128;
    int row = rem >> 2; int c = rem & 3;
    h8 z; 
    #pragma unroll
    for (int i=0;i<8;i++) z[i] = (_Float16)0.f;
    *(h8*)&As[m_][row][200 + c*8] = z;
  }
  __syncthreads();

  const int lane = tid & 63;
  const int jt = tid >> 6;          // 0..6
  const int jcol = lane & 31;
  const int kh = lane >> 5;         // k-half

  f16v acc[6];
  #pragma unroll
  for (int g=0;g<6;g++)
    #pragma unroll
    for (int r=0;r<16;r++) acc[g][r] = 0.f;

  const _Float16* bbase = Bp + ((size_t)jt*32 + jcol)*16 + kh*8;
  #pragma unroll
  for (int s=0; s<13; s++) {
    const h8 aA = *(const h8*)&As[0][jcol][s*16 + kh*8];
    const h8 aH = *(const h8*)&As[1][jcol][s*16 + kh*8];
    #pragma unroll
    for (int g=0; g<6; g++) {
      const h8 b = *(const h8*)(bbase + (size_t)(g*13 + s)*224*16);
      acc[g] = __builtin_amdgcn_mfma_f32_32x32x16_f16((g<3)?aA:aH, b, acc[g], 0,0,0);
    }
  }

  // epilogue: C/D col=lane&31, row=(reg&3)+8*(reg>>2)+4*(lane>>5)
  const int j = jt*32 + jcol;
  if (j < 200) {
    const float bri = bih[j],      brh = bhh[j];
    const float bzi = bih[200+j],  bzh = bhh[200+j];
    const float bni = bih[400+j],  bnh = bhh[400+j];
    #pragma unroll
    for (int r=0;r<16;r++) {
      const int row = (r&3) + 8*(r>>2) + 4*kh;
      const float rr = 1.f/(1.f+expf(-(acc[0][r]+bri + acc[3][r]+brh)));
      const float zz = 1.f/(1.f+expf(-(acc[1][r]+bzi + acc[4][r]+bzh)));
      const float nn = tanhf(acc[2][r]+bni + rr*(acc[5][r]+bnh));
      const float hv = (float)As[1][row][j];
      hnew[(size_t)(bm+row)*200 + j] = (_Float16)((1.f-zz)*nn + zz*hv);
    }
  }
}

// ---------------- head ----------------
// Xt[b][l(304)][p(224)] fp16: l<200 from hid, 200<=l<301 from x, else 0; p>=205 zero.
__global__ __launch_bounds__(256) void build_xt(const _Float16* __restrict__ hid,
        const float* __restrict__ x, _Float16* __restrict__ Xt) {
  __shared__ _Float16 T[32][34];
  int pt = blockIdx.x*32, lt = blockIdx.y*32, b = blockIdx.z;
  int lo = threadIdx.x & 31;
  int po = threadIdx.x >> 5;
  #pragma unroll
  for (int q=0;q<4;q++) {
    int p = pt + po + q*8;
    int l = lt + lo;
    _Float16 v = (_Float16)0.f;
    if (p < 205 && l < 301) {
      size_t node = (size_t)b*205 + p;
      v = (l < 200) ? hid[node*200 + l] : (_Float16)x[node*101 + (l-200)];
    }
    T[po + q*8][lo] = v;
  }
  __syncthreads();
  #pragma unroll
  for (int q=0;q<4;q++) {
    int l = lt + po + q*8;
    int p = pt + lo;
    if (l < 304)
      Xt[((size_t)b*304 + l)*224 + p] = T[lo][po + q*8];
  }
}

// out[b,o,t] = bias[o] + sum_{kc,p} W[o,p,kc] * Xt[b][t+kc-1][p]
__global__ __launch_bounds__(256) void conv1_mfma(const _Float16* __restrict__ Xt,
        const _Float16* __restrict__ Wp, const float* __restrict__ bias,
        int LIN, float* __restrict__ out) {
  int b = blockIdx.y;
  int t0 = blockIdx.x * 64;
  int lane = threadIdx.x & 63;
  int tt = threadIdx.x >> 6;
  int j = lane & 15;
  int kg = lane >> 4;
  int t = t0 + tt*16 + j;
  f4 acc[4];
  #pragma unroll
  for (int a=0;a<4;a++) { acc[a][0]=0.f; acc[a][1]=0.f; acc[a][2]=0.f; acc[a][3]=0.f; }
  const _Float16* xb = Xt + (size_t)b*304*224;
  #pragma unroll
  for (int s=0; s<21; s++) {
    const int kc = s/7;
    const int p0 = (s - kc*7)*32 + kg*8;
    const int tp = t + kc - 1;
    h8 bfrag = {0,0,0,0,0,0,0,0};
    if (tp >= 0 && tp < LIN) bfrag = *(const h8*)(xb + (size_t)tp*224 + p0);
    #pragma unroll
    for (int a=0;a<4;a++) {
      const h8 afrag = *(const h8*)(Wp + ((size_t)(s*64 + a*16 + j)*32 + kg*8));
      acc[a] = __builtin_amdgcn_mfma_f32_16x16x32_f16(afrag, bfrag, acc[a], 0,0,0);
    }
  }
  if (t < LIN) {
    #pragma unroll
    for (int a=0;a<4;a++) {
      #pragma unroll
      for (int r=0;r<4;r++) {
        int o = a*16 + kg*4 + r;
        if (o < 50) out[((size_t)b*50 + o)*LIN + t] = acc[a][r] + bias[o];
      }
    }
  }
}

__global__ void bn_stats(const float* __restrict__ v, int C, int L, float* __restrict__ sums) {
  int c = blockIdx.x;
  int bs = blockIdx.y * 32;
  float s = 0.f, s2 = 0.f;
  for (int idx = threadIdx.x; idx < 32*L; idx += 256) {
    int b = bs + idx / L, t = idx - (idx/L)*L;
    float val = v[((long)b*C + c)*L + t];
    s += val; s2 += val*val;
  }
  __shared__ float rs[256], rq[256];
  rs[threadIdx.x]=s; rq[threadIdx.x]=s2; __syncthreads();
  for (int d=128; d>0; d>>=1){
    if (threadIdx.x<d){ rs[threadIdx.x]+=rs[threadIdx.x+d]; rq[threadIdx.x]+=rq[threadIdx.x+d]; }
    __syncthreads();
  }
  if (threadIdx.x==0){ atomicAdd(&sums[2*c], rs[0]); atomicAdd(&sums[2*c+1], rq[0]); }
}

__global__ void bn_finalize(const float* __restrict__ sums, const float* __restrict__ g,
        const float* __restrict__ b, int C, float inv_n, float* __restrict__ scale, float* __restrict__ shift) {
  int c = threadIdx.x;
  if (c < C) {
    float mean = sums[2*c]*inv_n;
    float var = sums[2*c+1]*inv_n - mean*mean;
    float sc = g[c]*rsqrtf(var + 1e-5f);
    scale[c] = sc;
    shift[c] = b[c] - mean*sc;
  }
}

__global__ void bn_act_pool(const float* __restrict__ v, const float* __restrict__ sc,
      const float* __restrict__ sh, int C, int Lin, int Lout, int K, int do_relu, float* __restrict__ out) {
  int idx = blockIdx.x*256 + threadIdx.x;
  int total = BATCH*C*Lout;
  if (idx>=total) return;
  int t = idx % Lout; int r = idx / Lout; int c = r % C; int b = r / C;
  const float* src = v + ((long)(b*C + c))*Lin + 2*t;
  float m = -3.4e38f;
  for (int k=0;k<K;k++){
    float u = src[k]*sc[c] + sh[c];
    if (do_relu) u = (u>=0.f)? u : 0.01f*u;
    m = fmaxf(m,u);
  }
  out[idx] = m;
}

__global__ __launch_bounds__(256) void conv2_kernel(const float* __restrict__ in,
        const float* __restrict__ w, const float* __restrict__ b2, int Lm, float* __restrict__ out) {
  __shared__ float sw[1000];
  __shared__ float sin[50*150];
  int b = blockIdx.x;
  for (int i=threadIdx.x;i<1000;i+=256) sw[i]=w[i];
  for (int i=threadIdx.x;i<50*Lm;i+=256) sin[i] = in[(long)b*50*Lm + i];
  __syncthreads();
  int Lo = Lm + 2;
  for (int idx=threadIdx.x; idx<20*Lo; idx+=256) {
    int c = idx / Lo, t = idx - c*Lo;
    float acc = b2[c];
    if (t>=1 && t<=Lm) {
      const float* sp = sin + (t-1);
      const float* wp = sw + c*50;
      for (int i=0;i<50;i++) acc += wp[i]*sp[i*Lm];
    }
    out[(long)b*20*Lo + idx] = acc;
  }
}

__global__ void final_kernel(const float* __restrict__ Zf, const float* __restrict__ Yf,
        const float* __restrict__ fc1w, const float* __restrict__ fc1b,
        const float* __restrict__ fc2w, const float* __restrict__ fc2b, float* __restrict__ out) {
  int b = blockIdx.x;
  float s1=0.f, s2=0.f;
  for (int i=threadIdx.x;i<1520;i+=256) s1 += Zf[(long)b*1520+i]*fc1w[i];
  for (int i=threadIdx.x;i<1000;i+=256) s2 += Yf[(long)b*1000+i]*fc2w[i];
  __shared__ float r1[256], r2[256];
  r1[threadIdx.x]=s1; r2[threadIdx.x]=s2; __syncthreads();
  for (int d=128; d>0; d>>=1){
    if (threadIdx.x<d){ r1[threadIdx.x]+=r1[threadIdx.x+d]; r2[threadIdx.x]+=r2[threadIdx.x+d]; }
    __syncthreads();
  }
  if (threadIdx.x==0){
    float res = (r1[0]+fc1b[0])*(r2[0]+fc2b[0]);
    out[b] = 1.f/(1.f+expf(-res));
  }
}

// ---------------- launch ----------------
extern "C" void kernel_launch(void* const* d_in, const int* in_sizes, int n_in,
                              void* d_out, int out_size, void* d_ws, size_t ws_size,
                              hipStream_t stream) {
  const float* x    = (const float*)d_in[0];
  const int*   ei   = (const int*)d_in[1];
  const float* ggcw = (const float*)d_in[2];
  const float* wih  = (const float*)d_in[3];
  const float* whh  = (const float*)d_in[4];
  const float* bih  = (const float*)d_in[5];
  const float* bhh  = (const float*)d_in[6];
  const float* c1w  = (const float*)d_in[7];
  const float* c1b  = (const float*)d_in[8];
  const float* bn1g = (const float*)d_in[9];
  const float* bn1b = (const float*)d_in[10];
  const float* c2w  = (const float*)d_in[11];
  const float* c2b  = (const float*)d_in[12];
  const float* bn2g = (const float*)d_in[13];
  const float* bn2b = (const float*)d_in[14];
  const float* fc1w = (const float*)d_in[15];
  const float* fc1b = (const float*)d_in[16];
  const float* fc2w = (const float*)d_in[17];
  const float* fc2b = (const float*)d_in[18];
  float* out = (float*)d_out;

  char* ws = (char*)d_ws;
  size_t HS = (size_t)NN*OUT*2;                       // 41,984,000 B per h buffer
  _Float16* h0 = (_Float16*)ws;
  _Float16* h1 = (_Float16*)(ws + HS);
  _Float16* h2 = (_Float16*)(ws + 2*HS);
  _Float16* Xt = h1;                                  // overlay: 512*304*224*2 = 69.7 MB
  char* aux = ws + 3*HS;
  float*    Wf = (float*)aux;    aux += (size_t)6*200*600*4;
  _Float16* Bp = (_Float16*)aux; aux += (size_t)6*6*13*224*16*2;   // 3.35 MB
  _Float16* Wp1 = (_Float16*)aux; aux += (size_t)21*64*32*2;
  int* rowptr = (int*)aux;       aux += (size_t)(NN+16)*4;
  int* cursor = (int*)aux;       aux += (size_t)NN*4;
  int* col    = (int*)aux;       aux += (size_t)NE*4;
  float* sums = (float*)aux;     aux += 128*4;
  float* sc   = (float*)aux;     aux += 64*4;
  float* sh   = (float*)aux;     aux += 64*4;
  float* z_c1  = (float*)aux;
  float* y_c1  = z_c1  + (size_t)512*50*301;
  float* z_mp1 = y_c1  + (size_t)512*50*200;
  float* y_mp1 = z_mp1 + (size_t)512*50*150;
  float* z_c2  = y_mp1 + (size_t)512*50*99;
  float* y_c2  = z_c2  + (size_t)512*20*152;
  float* z_mp2 = y_c2  + (size_t)512*20*101;
  float* y_mp2 = z_mp2 + (size_t)512*1520;

  // precompute
  pad16<<<NN*OUT/256, 256, 0, stream>>>(x, h0);
  fuse_w_kernel<<<(6*200*600+255)/256, 256, 0, stream>>>(ggcw, wih, Wf);
  pack_b32<<<6*6*13*224*16/256, 256, 0, stream>>>(Wf, whh, Bp);
  pack_w1<<<(21*64*32+255)/256, 256, 0, stream>>>(c1w, Wp1);
  // CSR
  zero_i32<<<(NN+255)/256, 256, 0, stream>>>(cursor, NN);
  count_deg<<<NE/256, 256, 0, stream>>>(ei, cursor);
  scan_kernel<<<1, 1024, 0, stream>>>(cursor, rowptr);
  copy_i32<<<(NN+255)/256, 256, 0, stream>>>(rowptr, cursor, NN);
  fill_csr<<<NE/256, 256, 0, stream>>>(ei, cursor, col);

  // GGC layers
  _Float16* cur = h0; _Float16* other = h2;
  for (int i=0;i<LAYERS;i++){
    gather16<<<NN*25/256, 256, 0, stream>>>(cur, rowptr, col, h1);
    gru_mfma2<<<NN/32, 448, 0, stream>>>(h1, cur, Bp + (size_t)i*6*13*224*16,
                                         bih, bhh, other);
    _Float16* t = cur; cur = other; other = t;
  }
  // cur == h0 (final hidden, fp16); h1/h2 free -> Xt overlay

  // head
  build_xt<<<dim3(7, 10, BATCH), 256, 0, stream>>>(cur, x, Xt);
  conv1_mfma<<<dim3(5, BATCH), 256, 0, stream>>>(Xt, Wp1, c1b, 301, z_c1);
  conv1_mfma<<<dim3(4, BATCH), 256, 0, stream>>>(Xt, Wp1, c1b, 200, y_c1);

  zero_f32<<<1, 128, 0, stream>>>(sums, 128);
  bn_stats<<<dim3(50,16), 256, 0, stream>>>(z_c1, 50, 301, sums);
  bn_finalize<<<1, 64, 0, stream>>>(sums, bn1g, bn1b, 50, 1.f/(512.f*301.f), sc, sh);
  bn_act_pool<<<(512*50*150+255)/256, 256, 0, stream>>>(z_c1, sc, sh, 50, 301, 150, 3, 1, z_mp1);

  zero_f32<<<1, 128, 0, stream>>>(sums, 128);
  bn_stats<<<dim3(50,16), 256, 0, stream>>>(y_c1, 50, 200, sums);
  bn_finalize<<<1, 64, 0, stream>>>(sums, bn1g, bn1b, 50, 1.f/(512.f*200.f), sc, sh);
  bn_act_pool<<<(512*50*99+255)/256, 256, 0, stream>>>(y_c1, sc, sh, 50, 200, 99, 3, 1, y_mp1);

  conv2_kernel<<<BATCH, 256, 0, stream>>>(z_mp1, c2w, c2b, 150, z_c2);
  conv2_kernel<<<BATCH, 256, 0, stream>>>(y_mp1, c2w, c2b, 99, y_c2);

  zero_f32<<<1, 128, 0, stream>>>(sums, 128);
  bn_stats<<<dim3(20,16), 256, 0, stream>>>(z_c2, 20, 152, sums);
  bn_finalize<<<1, 64, 0, stream>>>(sums, bn2g, bn2b, 20, 1.f/(512.f*152.f), sc, sh);
  bn_act_pool<<<(512*20*76+255)/256, 256, 0, stream>>>(z_c2, sc, sh, 20, 152, 76, 2, 0, z_mp2);

  zero_f32<<<1, 128, 0, stream>>>(sums, 128);
  bn_stats<<<dim3(20,16), 256, 0, stream>>>(y_c2, 20, 101, sums);
  bn_finalize<<<1, 64, 0, stream>>>(sums, bn2g, bn2b, 20, 1.f/(512.f*101.f), sc, sh);
  bn_act_pool<<<(512*20*50+255)/256, 256, 0, stream>>>(y_c2, sc, sh, 20, 101, 50, 2, 0, y_mp2);

  final_kernel<<<BATCH, 256, 0, stream>>>(z_mp2, y_mp2, fc1w, fc1b, fc2w, fc2b, out);
}

// Round 5
// 1556.967 us; speedup vs baseline: 15.5492x; 1.1161x over previous
//
#include <hip/hip_runtime.h>
#include <math.h>

#define NN 104960      // nodes = 205 * 512
#define OUT 200
#define EMB 101
#define NPG 205
#define BATCH 512
#define NE 629760      // edges
#define LAYERS 6

typedef _Float16 h8 __attribute__((ext_vector_type(8)));
typedef float f4 __attribute__((ext_vector_type(4)));
typedef float f16v __attribute__((ext_vector_type(16)));

// ---------------- utility kernels ----------------
__global__ void zero_i32(int* p, int n){ int i=blockIdx.x*256+threadIdx.x; if(i<n) p[i]=0; }
__global__ void zero_f32(float* p, int n){ int i=blockIdx.x*blockDim.x+threadIdx.x; if(i<n) p[i]=0.f; }

// h[N,200] fp16 = pad(x[N,101])
__global__ void pad16(const float* __restrict__ x, _Float16* __restrict__ h) {
  int idx = blockIdx.x*256 + threadIdx.x;
  if (idx >= NN*OUT) return;
  int n = idx / OUT, j = idx - n*OUT;
  h[idx] = (j < EMB) ? (_Float16)x[n*EMB + j] : (_Float16)0.f;
}

// Wf[i][k][o] = sum_j ggc_w[i][k][j] * wih[o][j]   (i<6, k<200, o<600)  fp32
__global__ void fuse_w_kernel(const float* __restrict__ ggc_w, const float* __restrict__ wih,
                              float* __restrict__ Wf) {
  long idx = (long)blockIdx.x*256 + threadIdx.x;
  if (idx >= 6L*200*600) return;
  int o = (int)(idx % 600); long r = idx / 600; int k = (int)(r % 200); int i = (int)(r / 200);
  const float* wr = ggc_w + ((long)i*200 + k)*200;
  const float* vr = wih + (long)o*200;
  float acc = 0.f;
  for (int j=0;j<200;j++) acc += wr[j]*vr[j];
  Wf[idx] = acc;
}

// Bp32[layer][gate][s(13)][j(224)][k(16)] fp16 — 32-wide fragment order for 32x32x16 MFMA.
__global__ void pack_b32(const float* __restrict__ Wf, const float* __restrict__ whh,
                         _Float16* __restrict__ Bp) {
  size_t idx = (size_t)blockIdx.x*256 + threadIdx.x;
  if (idx >= 6UL*6*13*224*16) return;
  int kk = (int)(idx & 15); size_t r = idx >> 4;
  int j = (int)(r % 224); r /= 224;
  int s = (int)(r % 13);  r /= 13;
  int g = (int)(r % 6);   int l = (int)(r / 6);
  int k = s*16 + kk;
  float v = 0.f;
  if (k < 200 && j < 200) {
    v = (g < 3) ? Wf[(size_t)l*120000 + (size_t)k*600 + g*200 + j]
                : whh[((size_t)(g-3)*200 + j)*200 + k];
  }
  Bp[idx] = (_Float16)v;
}

// conv1 weights -> fragment order Wp[s(21)][o(64)][kk(32)] fp16
__global__ void pack_w1(const float* __restrict__ w, _Float16* __restrict__ Wp) {
  int idx = blockIdx.x*256 + threadIdx.x;   // 21*64*32 = 43008
  if (idx >= 21*64*32) return;
  int kk = idx & 31; int r = idx >> 5;
  int o = r & 63; int s = r >> 6;
  int kc = s/7, p = (s%7)*32 + kk;
  float v = 0.f;
  if (o < 50 && p < 205) v = w[o*615 + p*3 + kc];
  Wp[idx] = (_Float16)v;
}

// ---------------- CSR build ----------------
__global__ void count_deg(const int* __restrict__ ei, int* __restrict__ cnt) {
  int e = blockIdx.x*256+threadIdx.x;
  if (e < NE) atomicAdd(&cnt[ei[NE + e]], 1);
}

// hierarchical scan: NN = 205 blocks x 512
__global__ __launch_bounds__(512) void scan_block(const int* __restrict__ cnt,
        int* __restrict__ partial, int* __restrict__ bsum) {
  __shared__ int sd[512];
  int gi = blockIdx.x*512 + threadIdx.x;
  int v = cnt[gi];
  sd[threadIdx.x] = v;
  __syncthreads();
  #pragma unroll
  for (int d=1; d<512; d<<=1) {
    int t = (threadIdx.x>=d)? sd[threadIdx.x-d] : 0;
    __syncthreads();
    sd[threadIdx.x] += t;
    __syncthreads();
  }
  partial[gi] = sd[threadIdx.x] - v;              // exclusive within block
  if (threadIdx.x==511) bsum[blockIdx.x] = sd[511];
}

__global__ __launch_bounds__(256) void scan_bsum(int* __restrict__ bsum, int nb) {
  __shared__ int sd[256];
  int v = (threadIdx.x<nb)? bsum[threadIdx.x] : 0;
  sd[threadIdx.x] = v;
  __syncthreads();
  #pragma unroll
  for (int d=1; d<256; d<<=1) {
    int t = (threadIdx.x>=d)? sd[threadIdx.x-d] : 0;
    __syncthreads();
    sd[threadIdx.x] += t;
    __syncthreads();
  }
  if (threadIdx.x<nb) bsum[threadIdx.x] = sd[threadIdx.x] - v;   // exclusive
}

__global__ void scan_add(const int* __restrict__ partial, const int* __restrict__ bsum,
                         int* __restrict__ rowptr, int* __restrict__ cursor) {
  int i = blockIdx.x*256 + threadIdx.x;
  if (i < NN) {
    int v = partial[i] + bsum[i >> 9];
    rowptr[i] = v;
    cursor[i] = v;
  }
  if (i == 0) rowptr[NN] = NE;
}

__global__ void fill_csr(const int* __restrict__ ei, int* __restrict__ cursor, int* __restrict__ col) {
  int e = blockIdx.x*256+threadIdx.x;
  if (e < NE) {
    int dst = ei[NE+e], src = ei[e];
    int pos = atomicAdd(&cursor[dst], 1);
    col[pos] = src;
  }
}

// hagg[n,:] += h[col,:] ; thread = (node, 8-elem chunk), 25 chunks/node
__global__ void gather16(const _Float16* __restrict__ h, const int* __restrict__ rowptr,
                         const int* __restrict__ col, _Float16* __restrict__ out) {
  int idx = blockIdx.x*256 + threadIdx.x;
  if (idx >= NN*25) return;
  int n = idx / 25, c = idx - n*25;
  int s = rowptr[n], e = rowptr[n+1];
  float a[8];
  #pragma unroll
  for (int i=0;i<8;i++) a[i]=0.f;
  for (int p=s; p<e; ++p) {
    const h8 v = *(const h8*)(h + (size_t)col[p]*200 + c*8);
    #pragma unroll
    for (int i=0;i<8;i++) a[i] += (float)v[i];
  }
  h8 o;
  #pragma unroll
  for (int i=0;i<8;i++) o[i] = (_Float16)a[i];
  *(h8*)(out + (size_t)n*200 + c*8) = o;
}

// ---------------- MFMA fused GRU (32x32x16) ----------------
__global__ __launch_bounds__(448) void gru_mfma2(
    const _Float16* __restrict__ hagg, const _Float16* __restrict__ h,
    const _Float16* __restrict__ Bp,
    const float* __restrict__ bih, const float* __restrict__ bhh,
    _Float16* __restrict__ hnew) {
  __shared__ _Float16 As[2][32][232];
  const int tid = threadIdx.x;
  const int bm = blockIdx.x * 32;

  for (int idx = tid; idx < 1600; idx += 448) {     // 2*32*25 h8 chunks
    int m_ = idx / 800; int rem = idx - m_*800;
    int row = rem / 25; int kc = rem - row*25;
    const _Float16* src = m_ ? h : hagg;
    *(h8*)&As[m_][row][kc*8] = *(const h8*)(src + (size_t)(bm+row)*200 + kc*8);
  }
  for (int idx = tid; idx < 256; idx += 448) {      // zero pad k = 200..231
    int m_ = idx / 128; int rem = idx - m_*128;
    int row = rem >> 2; int c = rem & 3;
    h8 z;
    #pragma unroll
    for (int i=0;i<8;i++) z[i] = (_Float16)0.f;
    *(h8*)&As[m_][row][200 + c*8] = z;
  }
  __syncthreads();

  const int lane = tid & 63;
  const int jt = tid >> 6;          // 0..6
  const int jcol = lane & 31;
  const int kh = lane >> 5;         // k-half

  f16v acc[6];
  #pragma unroll
  for (int g=0;g<6;g++)
    #pragma unroll
    for (int r=0;r<16;r++) acc[g][r] = 0.f;

  const _Float16* bbase = Bp + ((size_t)jt*32 + jcol)*16 + kh*8;
  #pragma unroll
  for (int s=0; s<13; s++) {
    const h8 aA = *(const h8*)&As[0][jcol][s*16 + kh*8];
    const h8 aH = *(const h8*)&As[1][jcol][s*16 + kh*8];
    #pragma unroll
    for (int g=0; g<6; g++) {
      const h8 b = *(const h8*)(bbase + (size_t)(g*13 + s)*224*16);
      acc[g] = __builtin_amdgcn_mfma_f32_32x32x16_f16((g<3)?aA:aH, b, acc[g], 0,0,0);
    }
  }

  const int j = jt*32 + jcol;
  if (j < 200) {
    const float bri = bih[j],      brh = bhh[j];
    const float bzi = bih[200+j],  bzh = bhh[200+j];
    const float bni = bih[400+j],  bnh = bhh[400+j];
    #pragma unroll
    for (int r=0;r<16;r++) {
      const int row = (r&3) + 8*(r>>2) + 4*kh;
      const float rr = 1.f/(1.f+expf(-(acc[0][r]+bri + acc[3][r]+brh)));
      const float zz = 1.f/(1.f+expf(-(acc[1][r]+bzi + acc[4][r]+bzh)));
      const float nn = tanhf(acc[2][r]+bni + rr*(acc[5][r]+bnh));
      const float hv = (float)As[1][row][j];
      hnew[(size_t)(bm+row)*200 + j] = (_Float16)((1.f-zz)*nn + zz*hv);
    }
  }
}

// ---------------- head ----------------
__global__ __launch_bounds__(256) void build_xt(const _Float16* __restrict__ hid,
        const float* __restrict__ x, _Float16* __restrict__ Xt) {
  __shared__ _Float16 T[32][34];
  int pt = blockIdx.x*32, lt = blockIdx.y*32, b = blockIdx.z;
  int lo = threadIdx.x & 31;
  int po = threadIdx.x >> 5;
  #pragma unroll
  for (int q=0;q<4;q++) {
    int p = pt + po + q*8;
    int l = lt + lo;
    _Float16 v = (_Float16)0.f;
    if (p < 205 && l < 301) {
      size_t node = (size_t)b*205 + p;
      v = (l < 200) ? hid[node*200 + l] : (_Float16)x[node*101 + (l-200)];
    }
    T[po + q*8][lo] = v;
  }
  __syncthreads();
  #pragma unroll
  for (int q=0;q<4;q++) {
    int l = lt + po + q*8;
    int p = pt + lo;
    if (l < 304)
      Xt[((size_t)b*304 + l)*224 + p] = T[lo][po + q*8];
  }
}

__global__ __launch_bounds__(256) void conv1_mfma(const _Float16* __restrict__ Xt,
        const _Float16* __restrict__ Wp, const float* __restrict__ bias,
        int LIN, float* __restrict__ out) {
  int b = blockIdx.y;
  int t0 = blockIdx.x * 64;
  int lane = threadIdx.x & 63;
  int tt = threadIdx.x >> 6;
  int j = lane & 15;
  int kg = lane >> 4;
  int t = t0 + tt*16 + j;
  f4 acc[4];
  #pragma unroll
  for (int a=0;a<4;a++) { acc[a][0]=0.f; acc[a][1]=0.f; acc[a][2]=0.f; acc[a][3]=0.f; }
  const _Float16* xb = Xt + (size_t)b*304*224;
  #pragma unroll
  for (int s=0; s<21; s++) {
    const int kc = s/7;
    const int p0 = (s - kc*7)*32 + kg*8;
    const int tp = t + kc - 1;
    h8 bfrag = {0,0,0,0,0,0,0,0};
    if (tp >= 0 && tp < LIN) bfrag = *(const h8*)(xb + (size_t)tp*224 + p0);
    #pragma unroll
    for (int a=0;a<4;a++) {
      const h8 afrag = *(const h8*)(Wp + ((size_t)(s*64 + a*16 + j)*32 + kg*8));
      acc[a] = __builtin_amdgcn_mfma_f32_16x16x32_f16(afrag, bfrag, acc[a], 0,0,0);
    }
  }
  if (t < LIN) {
    #pragma unroll
    for (int a=0;a<4;a++) {
      #pragma unroll
      for (int r=0;r<4;r++) {
        int o = a*16 + kg*4 + r;
        if (o < 50) out[((size_t)b*50 + o)*LIN + t] = acc[a][r] + bias[o];
      }
    }
  }
}

__global__ void bn_stats(const float* __restrict__ v, int C, int L, float* __restrict__ sums) {
  int c = blockIdx.x;
  int bs = blockIdx.y * 32;
  float s = 0.f, s2 = 0.f;
  for (int idx = threadIdx.x; idx < 32*L; idx += 256) {
    int b = bs + idx / L, t = idx - (idx/L)*L;
    float val = v[((long)b*C + c)*L + t];
    s += val; s2 += val*val;
  }
  __shared__ float rs[256], rq[256];
  rs[threadIdx.x]=s; rq[threadIdx.x]=s2; __syncthreads();
  for (int d=128; d>0; d>>=1){
    if (threadIdx.x<d){ rs[threadIdx.x]+=rs[threadIdx.x+d]; rq[threadIdx.x]+=rq[threadIdx.x+d]; }
    __syncthreads();
  }
  if (threadIdx.x==0){ atomicAdd(&sums[2*c], rs[0]); atomicAdd(&sums[2*c+1], rq[0]); }
}

__global__ void bn_finalize(const float* __restrict__ sums, const float* __restrict__ g,
        const float* __restrict__ b, int C, float inv_n, float* __restrict__ scale, float* __restrict__ shift) {
  int c = threadIdx.x;
  if (c < C) {
    float mean = sums[2*c]*inv_n;
    float var = sums[2*c+1]*inv_n - mean*mean;
    float sc = g[c]*rsqrtf(var + 1e-5f);
    scale[c] = sc;
    shift[c] = b[c] - mean*sc;
  }
}

__global__ void bn_act_pool(const float* __restrict__ v, const float* __restrict__ sc,
      const float* __restrict__ sh, int C, int Lin, int Lout, int K, int do_relu, float* __restrict__ out) {
  int idx = blockIdx.x*256 + threadIdx.x;
  int total = BATCH*C*Lout;
  if (idx>=total) return;
  int t = idx % Lout; int r = idx / Lout; int c = r % C; int b = r / C;
  const float* src = v + ((long)(b*C + c))*Lin + 2*t;
  float m = -3.4e38f;
  for (int k=0;k<K;k++){
    float u = src[k]*sc[c] + sh[c];
    if (do_relu) u = (u>=0.f)? u : 0.01f*u;
    m = fmaxf(m,u);
  }
  out[idx] = m;
}

__global__ __launch_bounds__(256) void conv2_kernel(const float* __restrict__ in,
        const float* __restrict__ w, const float* __restrict__ b2, int Lm, float* __restrict__ out) {
  __shared__ float sw[1000];
  __shared__ float sin[50*150];
  int b = blockIdx.x;
  for (int i=threadIdx.x;i<1000;i+=256) sw[i]=w[i];
  for (int i=threadIdx.x;i<50*Lm;i+=256) sin[i] = in[(long)b*50*Lm + i];
  __syncthreads();
  int Lo = Lm + 2;
  for (int idx=threadIdx.x; idx<20*Lo; idx+=256) {
    int c = idx / Lo, t = idx - c*Lo;
    float acc = b2[c];
    if (t>=1 && t<=Lm) {
      const float* sp = sin + (t-1);
      const float* wp = sw + c*50;
      for (int i=0;i<50;i++) acc += wp[i]*sp[i*Lm];
    }
    out[(long)b*20*Lo + idx] = acc;
  }
}

__global__ void final_kernel(const float* __restrict__ Zf, const float* __restrict__ Yf,
        const float* __restrict__ fc1w, const float* __restrict__ fc1b,
        const float* __restrict__ fc2w, const float* __restrict__ fc2b, float* __restrict__ out) {
  int b = blockIdx.x;
  float s1=0.f, s2=0.f;
  for (int i=threadIdx.x;i<1520;i+=256) s1 += Zf[(long)b*1520+i]*fc1w[i];
  for (int i=threadIdx.x;i<1000;i+=256) s2 += Yf[(long)b*1000+i]*fc2w[i];
  __shared__ float r1[256], r2[256];
  r1[threadIdx.x]=s1; r2[threadIdx.x]=s2; __syncthreads();
  for (int d=128; d>0; d>>=1){
    if (threadIdx.x<d){ r1[threadIdx.x]+=r1[threadIdx.x+d]; r2[threadIdx.x]+=r2[threadIdx.x+d]; }
    __syncthreads();
  }
  if (threadIdx.x==0){
    float res = (r1[0]+fc1b[0])*(r2[0]+fc2b[0]);
    out[b] = 1.f/(1.f+expf(-res));
  }
}

// ---------------- launch ----------------
extern "C" void kernel_launch(void* const* d_in, const int* in_sizes, int n_in,
                              void* d_out, int out_size, void* d_ws, size_t ws_size,
                              hipStream_t stream) {
  const float* x    = (const float*)d_in[0];
  const int*   ei   = (const int*)d_in[1];
  const float* ggcw = (const float*)d_in[2];
  const float* wih  = (const float*)d_in[3];
  const float* whh  = (const float*)d_in[4];
  const float* bih  = (const float*)d_in[5];
  const float* bhh  = (const float*)d_in[6];
  const float* c1w  = (const float*)d_in[7];
  const float* c1b  = (const float*)d_in[8];
  const float* bn1g = (const float*)d_in[9];
  const float* bn1b = (const float*)d_in[10];
  const float* c2w  = (const float*)d_in[11];
  const float* c2b  = (const float*)d_in[12];
  const float* bn2g = (const float*)d_in[13];
  const float* bn2b = (const float*)d_in[14];
  const float* fc1w = (const float*)d_in[15];
  const float* fc1b = (const float*)d_in[16];
  const float* fc2w = (const float*)d_in[17];
  const float* fc2b = (const float*)d_in[18];
  float* out = (float*)d_out;

  char* ws = (char*)d_ws;
  size_t HS = (size_t)NN*OUT*2;                       // 41,984,000 B per h buffer
  _Float16* h0 = (_Float16*)ws;
  _Float16* h1 = (_Float16*)(ws + HS);
  _Float16* h2 = (_Float16*)(ws + 2*HS);
  _Float16* Xt = h1;                                  // overlay: 512*304*224*2 = 69.7 MB
  char* aux = ws + 3*HS;
  float*    Wf = (float*)aux;    aux += (size_t)6*200*600*4;
  _Float16* Bp = (_Float16*)aux; aux += (size_t)6*6*13*224*16*2;   // 3.35 MB
  _Float16* Wp1 = (_Float16*)aux; aux += (size_t)21*64*32*2;
  int* deg    = (int*)aux;       aux += (size_t)NN*4;
  int* part   = (int*)aux;       aux += (size_t)NN*4;
  int* bsum   = (int*)aux;       aux += 256*4;
  int* rowptr = (int*)aux;       aux += (size_t)(NN+16)*4;
  int* cursor = (int*)aux;       aux += (size_t)NN*4;
  int* col    = (int*)aux;       aux += (size_t)NE*4;
  float* sums = (float*)aux;     aux += 128*4;
  float* sc   = (float*)aux;     aux += 64*4;
  float* sh   = (float*)aux;     aux += 64*4;
  float* z_c1  = (float*)aux;
  float* y_c1  = z_c1  + (size_t)512*50*301;
  float* z_mp1 = y_c1  + (size_t)512*50*200;
  float* y_mp1 = z_mp1 + (size_t)512*50*150;
  float* z_c2  = y_mp1 + (size_t)512*50*99;
  float* y_c2  = z_c2  + (size_t)512*20*152;
  float* z_mp2 = y_c2  + (size_t)512*20*101;
  float* y_mp2 = z_mp2 + (size_t)512*1520;

  // precompute
  pad16<<<NN*OUT/256, 256, 0, stream>>>(x, h0);
  fuse_w_kernel<<<(6*200*600+255)/256, 256, 0, stream>>>(ggcw, wih, Wf);
  pack_b32<<<6*6*13*224*16/256, 256, 0, stream>>>(Wf, whh, Bp);
  pack_w1<<<(21*64*32+255)/256, 256, 0, stream>>>(c1w, Wp1);
  // CSR (hierarchical scan)
  zero_i32<<<(NN+255)/256, 256, 0, stream>>>(deg, NN);
  count_deg<<<NE/256, 256, 0, stream>>>(ei, deg);
  scan_block<<<NN/512, 512, 0, stream>>>(deg, part, bsum);
  scan_bsum<<<1, 256, 0, stream>>>(bsum, NN/512);
  scan_add<<<(NN+255)/256, 256, 0, stream>>>(part, bsum, rowptr, cursor);
  fill_csr<<<NE/256, 256, 0, stream>>>(ei, cursor, col);

  // GGC layers
  _Float16* cur = h0; _Float16* other = h2;
  for (int i=0;i<LAYERS;i++){
    gather16<<<NN*25/256, 256, 0, stream>>>(cur, rowptr, col, h1);
    gru_mfma2<<<NN/32, 448, 0, stream>>>(h1, cur, Bp + (size_t)i*6*13*224*16,
                                         bih, bhh, other);
    _Float16* t = cur; cur = other; other = t;
  }
  // cur == h0 (final hidden, fp16); h1/h2 free -> Xt overlay

  // head
  build_xt<<<dim3(7, 10, BATCH), 256, 0, stream>>>(cur, x, Xt);
  conv1_mfma<<<dim3(5, BATCH), 256, 0, stream>>>(Xt, Wp1, c1b, 301, z_c1);
  conv1_mfma<<<dim3(4, BATCH), 256, 0, stream>>>(Xt, Wp1, c1b, 200, y_c1);

  zero_f32<<<1, 128, 0, stream>>>(sums, 128);
  bn_stats<<<dim3(50,16), 256, 0, stream>>>(z_c1, 50, 301, sums);
  bn_finalize<<<1, 64, 0, stream>>>(sums, bn1g, bn1b, 50, 1.f/(512.f*301.f), sc, sh);
  bn_act_pool<<<(512*50*150+255)/256, 256, 0, stream>>>(z_c1, sc, sh, 50, 301, 150, 3, 1, z_mp1);

  zero_f32<<<1, 128, 0, stream>>>(sums, 128);
  bn_stats<<<dim3(50,16), 256, 0, stream>>>(y_c1, 50, 200, sums);
  bn_finalize<<<1, 64, 0, stream>>>(sums, bn1g, bn1b, 50, 1.f/(512.f*200.f), sc, sh);
  bn_act_pool<<<(512*50*99+255)/256, 256, 0, stream>>>(y_c1, sc, sh, 50, 200, 99, 3, 1, y_mp1);

  conv2_kernel<<<BATCH, 256, 0, stream>>>(z_mp1, c2w, c2b, 150, z_c2);
  conv2_kernel<<<BATCH, 256, 0, stream>>>(y_mp1, c2w, c2b, 99, y_c2);

  zero_f32<<<1, 128, 0, stream>>>(sums, 128);
  bn_stats<<<dim3(20,16), 256, 0, stream>>>(z_c2, 20, 152, sums);
  bn_finalize<<<1, 64, 0, stream>>>(sums, bn2g, bn2b, 20, 1.f/(512.f*152.f), sc, sh);
  bn_act_pool<<<(512*20*76+255)/256, 256, 0, stream>>>(z_c2, sc, sh, 20, 152, 76, 2, 0, z_mp2);

  zero_f32<<<1, 128, 0, stream>>>(sums, 128);
  bn_stats<<<dim3(20,16), 256, 0, stream>>>(y_c2, 20, 101, sums);
  bn_finalize<<<1, 64, 0, stream>>>(sums, bn2g, bn2b, 20, 1.f/(512.f*101.f), sc, sh);
  bn_act_pool<<<(512*20*50+255)/256, 256, 0, stream>>>(y_c2, sc, sh, 20, 101, 50, 2, 0, y_mp2);

  final_kernel<<<BATCH, 256, 0, stream>>>(z_mp2, y_mp2, fc1w, fc1b, fc2w, fc2b, out);
}

// Round 6
// 1547.005 us; speedup vs baseline: 15.6493x; 1.0064x over previous
//
#include <hip/hip_runtime.h>
#include <math.h>

#define NN 104960      // nodes = 205 * 512
#define OUT 200
#define EMB 101
#define NPG 205
#define BATCH 512
#define NE 629760      // edges
#define LAYERS 6

typedef _Float16 h8 __attribute__((ext_vector_type(8)));
typedef float f4 __attribute__((ext_vector_type(4)));
typedef float f16v __attribute__((ext_vector_type(16)));

// fast transcendentals on native v_exp_f32 / v_rcp_f32
__device__ __forceinline__ float fsig(float x) {
  return __builtin_amdgcn_rcpf(1.f + __builtin_amdgcn_exp2f(-1.44269504f*x));
}
__device__ __forceinline__ float ftanh(float x) {
  float e = __builtin_amdgcn_exp2f(2.88539008f*x);      // e^(2x)
  return 1.f - 2.f*__builtin_amdgcn_rcpf(e + 1.f);
}

// ---------------- utility kernels ----------------
__global__ void zero_i32(int* p, int n){ int i=blockIdx.x*256+threadIdx.x; if(i<n) p[i]=0; }
__global__ void zero_f32(float* p, int n){ int i=blockIdx.x*blockDim.x+threadIdx.x; if(i<n) p[i]=0.f; }

// h[N,200] fp16 = pad(x[N,101])
__global__ void pad16(const float* __restrict__ x, _Float16* __restrict__ h) {
  int idx = blockIdx.x*256 + threadIdx.x;
  if (idx >= NN*OUT) return;
  int n = idx / OUT, j = idx - n*OUT;
  h[idx] = (j < EMB) ? (_Float16)x[n*EMB + j] : (_Float16)0.f;
}

// Wf[i][k][o] = sum_j ggc_w[i][k][j] * wih[o][j]   (i<6, k<200, o<600)  fp32
__global__ void fuse_w_kernel(const float* __restrict__ ggc_w, const float* __restrict__ wih,
                              float* __restrict__ Wf) {
  long idx = (long)blockIdx.x*256 + threadIdx.x;
  if (idx >= 6L*200*600) return;
  int o = (int)(idx % 600); long r = idx / 600; int k = (int)(r % 200); int i = (int)(r / 200);
  const float* wr = ggc_w + ((long)i*200 + k)*200;
  const float* vr = wih + (long)o*200;
  float acc = 0.f;
  for (int j=0;j<200;j++) acc += wr[j]*vr[j];
  Wf[idx] = acc;
}

// Bp32[layer][gate][s(13)][j(224)][k(16)] fp16 — 32-wide fragment order for 32x32x16 MFMA.
__global__ void pack_b32(const float* __restrict__ Wf, const float* __restrict__ whh,
                         _Float16* __restrict__ Bp) {
  size_t idx = (size_t)blockIdx.x*256 + threadIdx.x;
  if (idx >= 6UL*6*13*224*16) return;
  int kk = (int)(idx & 15); size_t r = idx >> 4;
  int j = (int)(r % 224); r /= 224;
  int s = (int)(r % 13);  r /= 13;
  int g = (int)(r % 6);   int l = (int)(r / 6);
  int k = s*16 + kk;
  float v = 0.f;
  if (k < 200 && j < 200) {
    v = (g < 3) ? Wf[(size_t)l*120000 + (size_t)k*600 + g*200 + j]
                : whh[((size_t)(g-3)*200 + j)*200 + k];
  }
  Bp[idx] = (_Float16)v;
}

// conv1 weights -> fragment order Wp[s(21)][o(64)][kk(32)] fp16
__global__ void pack_w1(const float* __restrict__ w, _Float16* __restrict__ Wp) {
  int idx = blockIdx.x*256 + threadIdx.x;   // 21*64*32 = 43008
  if (idx >= 21*64*32) return;
  int kk = idx & 31; int r = idx >> 5;
  int o = r & 63; int s = r >> 6;
  int kc = s/7, p = (s%7)*32 + kk;
  float v = 0.f;
  if (o < 50 && p < 205) v = w[o*615 + p*3 + kc];
  Wp[idx] = (_Float16)v;
}

// ---------------- CSR build ----------------
__global__ void count_deg(const int* __restrict__ ei, int* __restrict__ cnt) {
  int e = blockIdx.x*256+threadIdx.x;
  if (e < NE) atomicAdd(&cnt[ei[NE + e]], 1);
}

// hierarchical scan: NN = 205 blocks x 512
__global__ __launch_bounds__(512) void scan_block(const int* __restrict__ cnt,
        int* __restrict__ partial, int* __restrict__ bsum) {
  __shared__ int sd[512];
  int gi = blockIdx.x*512 + threadIdx.x;
  int v = cnt[gi];
  sd[threadIdx.x] = v;
  __syncthreads();
  #pragma unroll
  for (int d=1; d<512; d<<=1) {
    int t = (threadIdx.x>=d)? sd[threadIdx.x-d] : 0;
    __syncthreads();
    sd[threadIdx.x] += t;
    __syncthreads();
  }
  partial[gi] = sd[threadIdx.x] - v;              // exclusive within block
  if (threadIdx.x==511) bsum[blockIdx.x] = sd[511];
}

__global__ __launch_bounds__(256) void scan_bsum(int* __restrict__ bsum, int nb) {
  __shared__ int sd[256];
  int v = (threadIdx.x<nb)? bsum[threadIdx.x] : 0;
  sd[threadIdx.x] = v;
  __syncthreads();
  #pragma unroll
  for (int d=1; d<256; d<<=1) {
    int t = (threadIdx.x>=d)? sd[threadIdx.x-d] : 0;
    __syncthreads();
    sd[threadIdx.x] += t;
    __syncthreads();
  }
  if (threadIdx.x<nb) bsum[threadIdx.x] = sd[threadIdx.x] - v;   // exclusive
}

__global__ void scan_add(const int* __restrict__ partial, const int* __restrict__ bsum,
                         int* __restrict__ rowptr, int* __restrict__ cursor) {
  int i = blockIdx.x*256 + threadIdx.x;
  if (i < NN) {
    int v = partial[i] + bsum[i >> 9];
    rowptr[i] = v;
    cursor[i] = v;
  }
  if (i == 0) rowptr[NN] = NE;
}

__global__ void fill_csr(const int* __restrict__ ei, int* __restrict__ cursor, int* __restrict__ col) {
  int e = blockIdx.x*256+threadIdx.x;
  if (e < NE) {
    int dst = ei[NE+e], src = ei[e];
    int pos = atomicAdd(&cursor[dst], 1);
    col[pos] = src;
  }
}

// hagg[n,:] += h[col,:] ; thread = (node, 8-elem chunk), 25 chunks/node
__global__ void gather16(const _Float16* __restrict__ h, const int* __restrict__ rowptr,
                         const int* __restrict__ col, _Float16* __restrict__ out) {
  int idx = blockIdx.x*256 + threadIdx.x;
  if (idx >= NN*25) return;
  int n = idx / 25, c = idx - n*25;
  int s = rowptr[n], e = rowptr[n+1];
  float a[8];
  #pragma unroll
  for (int i=0;i<8;i++) a[i]=0.f;
  for (int p=s; p<e; ++p) {
    const h8 v = *(const h8*)(h + (size_t)col[p]*200 + c*8);
    #pragma unroll
    for (int i=0;i<8;i++) a[i] += (float)v[i];
  }
  h8 o;
  #pragma unroll
  for (int i=0;i<8;i++) o[i] = (_Float16)a[i];
  *(h8*)(out + (size_t)n*200 + c*8) = o;
}

// ---------------- MFMA fused GRU (32x32x16) ----------------
__global__ __launch_bounds__(448) void gru_mfma2(
    const _Float16* __restrict__ hagg, const _Float16* __restrict__ h,
    const _Float16* __restrict__ Bp,
    const float* __restrict__ bih, const float* __restrict__ bhh,
    _Float16* __restrict__ hnew) {
  __shared__ _Float16 As[2][32][232];
  const int tid = threadIdx.x;
  const int bm = blockIdx.x * 32;

  for (int idx = tid; idx < 1600; idx += 448) {     // 2*32*25 h8 chunks
    int m_ = idx / 800; int rem = idx - m_*800;
    int row = rem / 25; int kc = rem - row*25;
    const _Float16* src = m_ ? h : hagg;
    *(h8*)&As[m_][row][kc*8] = *(const h8*)(src + (size_t)(bm+row)*200 + kc*8);
  }
  for (int idx = tid; idx < 256; idx += 448) {      // zero pad k = 200..231
    int m_ = idx / 128; int rem = idx - m_*128;
    int row = rem >> 2; int c = rem & 3;
    h8 z;
    #pragma unroll
    for (int i=0;i<8;i++) z[i] = (_Float16)0.f;
    *(h8*)&As[m_][row][200 + c*8] = z;
  }
  __syncthreads();

  const int lane = tid & 63;
  const int jt = tid >> 6;          // 0..6
  const int jcol = lane & 31;
  const int kh = lane >> 5;         // k-half

  f16v acc[6];
  #pragma unroll
  for (int g=0;g<6;g++)
    #pragma unroll
    for (int r=0;r<16;r++) acc[g][r] = 0.f;

  const _Float16* bbase = Bp + ((size_t)jt*32 + jcol)*16 + kh*8;
  #pragma unroll
  for (int s=0; s<13; s++) {
    const h8 aA = *(const h8*)&As[0][jcol][s*16 + kh*8];
    const h8 aH = *(const h8*)&As[1][jcol][s*16 + kh*8];
    #pragma unroll
    for (int g=0; g<6; g++) {
      const h8 b = *(const h8*)(bbase + (size_t)(g*13 + s)*224*16);
      acc[g] = __builtin_amdgcn_mfma_f32_32x32x16_f16((g<3)?aA:aH, b, acc[g], 0,0,0);
    }
  }

  const int j = jt*32 + jcol;
  if (j < 200) {
    const float bri = bih[j],      brh = bhh[j];
    const float bzi = bih[200+j],  bzh = bhh[200+j];
    const float bni = bih[400+j],  bnh = bhh[400+j];
    #pragma unroll
    for (int r=0;r<16;r++) {
      const int row = (r&3) + 8*(r>>2) + 4*kh;
      const float rr = fsig(acc[0][r]+bri + acc[3][r]+brh);
      const float zz = fsig(acc[1][r]+bzi + acc[4][r]+bzh);
      const float nn = ftanh(acc[2][r]+bni + rr*(acc[5][r]+bnh));
      const float hv = (float)As[1][row][j];
      hnew[(size_t)(bm+row)*200 + j] = (_Float16)((1.f-zz)*nn + zz*hv);
    }
  }
}

// ---------------- head ----------------
__global__ __launch_bounds__(256) void build_xt(const _Float16* __restrict__ hid,
        const float* __restrict__ x, _Float16* __restrict__ Xt) {
  __shared__ _Float16 T[32][34];
  int pt = blockIdx.x*32, lt = blockIdx.y*32, b = blockIdx.z;
  int lo = threadIdx.x & 31;
  int po = threadIdx.x >> 5;
  #pragma unroll
  for (int q=0;q<4;q++) {
    int p = pt + po + q*8;
    int l = lt + lo;
    _Float16 v = (_Float16)0.f;
    if (p < 205 && l < 301) {
      size_t node = (size_t)b*205 + p;
      v = (l < 200) ? hid[node*200 + l] : (_Float16)x[node*101 + (l-200)];
    }
    T[po + q*8][lo] = v;
  }
  __syncthreads();
  #pragma unroll
  for (int q=0;q<4;q++) {
    int l = lt + po + q*8;
    int p = pt + lo;
    if (l < 304)
      Xt[((size_t)b*304 + l)*224 + p] = T[lo][po + q*8];
  }
}

__global__ __launch_bounds__(256) void conv1_mfma(const _Float16* __restrict__ Xt,
        const _Float16* __restrict__ Wp, const float* __restrict__ bias,
        int LIN, float* __restrict__ out) {
  int b = blockIdx.y;
  int t0 = blockIdx.x * 64;
  int lane = threadIdx.x & 63;
  int tt = threadIdx.x >> 6;
  int j = lane & 15;
  int kg = lane >> 4;
  int t = t0 + tt*16 + j;
  f4 acc[4];
  #pragma unroll
  for (int a=0;a<4;a++) { acc[a][0]=0.f; acc[a][1]=0.f; acc[a][2]=0.f; acc[a][3]=0.f; }
  const _Float16* xb = Xt + (size_t)b*304*224;
  #pragma unroll
  for (int s=0; s<21; s++) {
    const int kc = s/7;
    const int p0 = (s - kc*7)*32 + kg*8;
    const int tp = t + kc - 1;
    h8 bfrag = {0,0,0,0,0,0,0,0};
    if (tp >= 0 && tp < LIN) bfrag = *(const h8*)(xb + (size_t)tp*224 + p0);
    #pragma unroll
    for (int a=0;a<4;a++) {
      const h8 afrag = *(const h8*)(Wp + ((size_t)(s*64 + a*16 + j)*32 + kg*8));
      acc[a] = __builtin_amdgcn_mfma_f32_16x16x32_f16(afrag, bfrag, acc[a], 0,0,0);
    }
  }
  if (t < LIN) {
    #pragma unroll
    for (int a=0;a<4;a++) {
      #pragma unroll
      for (int r=0;r<4;r++) {
        int o = a*16 + kg*4 + r;
        if (o < 50) out[((size_t)b*50 + o)*LIN + t] = acc[a][r] + bias[o];
      }
    }
  }
}

__global__ void bn_stats(const float* __restrict__ v, int C, int L, float* __restrict__ sums) {
  int c = blockIdx.x;
  int bs = blockIdx.y * 32;
  float s = 0.f, s2 = 0.f;
  for (int idx = threadIdx.x; idx < 32*L; idx += 256) {
    int b = bs + idx / L, t = idx - (idx/L)*L;
    float val = v[((long)b*C + c)*L + t];
    s += val; s2 += val*val;
  }
  __shared__ float rs[256], rq[256];
  rs[threadIdx.x]=s; rq[threadIdx.x]=s2; __syncthreads();
  for (int d=128; d>0; d>>=1){
    if (threadIdx.x<d){ rs[threadIdx.x]+=rs[threadIdx.x+d]; rq[threadIdx.x]+=rq[threadIdx.x+d]; }
    __syncthreads();
  }
  if (threadIdx.x==0){ atomicAdd(&sums[2*c], rs[0]); atomicAdd(&sums[2*c+1], rq[0]); }
}

__global__ void bn_finalize(const float* __restrict__ sums, const float* __restrict__ g,
        const float* __restrict__ b, int C, float inv_n, float* __restrict__ scale, float* __restrict__ shift) {
  int c = threadIdx.x;
  if (c < C) {
    float mean = sums[2*c]*inv_n;
    float var = sums[2*c+1]*inv_n - mean*mean;
    float sc = g[c]*rsqrtf(var + 1e-5f);
    scale[c] = sc;
    shift[c] = b[c] - mean*sc;
  }
}

__global__ void bn_act_pool(const float* __restrict__ v, const float* __restrict__ sc,
      const float* __restrict__ sh, int C, int Lin, int Lout, int K, int do_relu, float* __restrict__ out) {
  int idx = blockIdx.x*256 + threadIdx.x;
  int total = BATCH*C*Lout;
  if (idx>=total) return;
  int t = idx % Lout; int r = idx / Lout; int c = r % C; int b = r / C;
  const float* src = v + ((long)(b*C + c))*Lin + 2*t;
  float m = -3.4e38f;
  for (int k=0;k<K;k++){
    float u = src[k]*sc[c] + sh[c];
    if (do_relu) u = (u>=0.f)? u : 0.01f*u;
    m = fmaxf(m,u);
  }
  out[idx] = m;
}

__global__ __launch_bounds__(256) void conv2_kernel(const float* __restrict__ in,
        const float* __restrict__ w, const float* __restrict__ b2, int Lm, float* __restrict__ out) {
  __shared__ float sw[1000];
  __shared__ float sin[50*150];
  int b = blockIdx.x;
  for (int i=threadIdx.x;i<1000;i+=256) sw[i]=w[i];
  for (int i=threadIdx.x;i<50*Lm;i+=256) sin[i] = in[(long)b*50*Lm + i];
  __syncthreads();
  int Lo = Lm + 2;
  for (int idx=threadIdx.x; idx<20*Lo; idx+=256) {
    int c = idx / Lo, t = idx - c*Lo;
    float acc = b2[c];
    if (t>=1 && t<=Lm) {
      const float* sp = sin + (t-1);
      const float* wp = sw + c*50;
      for (int i=0;i<50;i++) acc += wp[i]*sp[i*Lm];
    }
    out[(long)b*20*Lo + idx] = acc;
  }
}

__global__ void final_kernel(const float* __restrict__ Zf, const float* __restrict__ Yf,
        const float* __restrict__ fc1w, const float* __restrict__ fc1b,
        const float* __restrict__ fc2w, const float* __restrict__ fc2b, float* __restrict__ out) {
  int b = blockIdx.x;
  float s1=0.f, s2=0.f;
  for (int i=threadIdx.x;i<1520;i+=256) s1 += Zf[(long)b*1520+i]*fc1w[i];
  for (int i=threadIdx.x;i<1000;i+=256) s2 += Yf[(long)b*1000+i]*fc2w[i];
  __shared__ float r1[256], r2[256];
  r1[threadIdx.x]=s1; r2[threadIdx.x]=s2; __syncthreads();
  for (int d=128; d>0; d>>=1){
    if (threadIdx.x<d){ r1[threadIdx.x]+=r1[threadIdx.x+d]; r2[threadIdx.x]+=r2[threadIdx.x+d]; }
    __syncthreads();
  }
  if (threadIdx.x==0){
    float res = (r1[0]+fc1b[0])*(r2[0]+fc2b[0]);
    out[b] = fsig(res);
  }
}

// ---------------- launch ----------------
extern "C" void kernel_launch(void* const* d_in, const int* in_sizes, int n_in,
                              void* d_out, int out_size, void* d_ws, size_t ws_size,
                              hipStream_t stream) {
  const float* x    = (const float*)d_in[0];
  const int*   ei   = (const int*)d_in[1];
  const float* ggcw = (const float*)d_in[2];
  const float* wih  = (const float*)d_in[3];
  const float* whh  = (const float*)d_in[4];
  const float* bih  = (const float*)d_in[5];
  const float* bhh  = (const float*)d_in[6];
  const float* c1w  = (const float*)d_in[7];
  const float* c1b  = (const float*)d_in[8];
  const float* bn1g = (const float*)d_in[9];
  const float* bn1b = (const float*)d_in[10];
  const float* c2w  = (const float*)d_in[11];
  const float* c2b  = (const float*)d_in[12];
  const float* bn2g = (const float*)d_in[13];
  const float* bn2b = (const float*)d_in[14];
  const float* fc1w = (const float*)d_in[15];
  const float* fc1b = (const float*)d_in[16];
  const float* fc2w = (const float*)d_in[17];
  const float* fc2b = (const float*)d_in[18];
  float* out = (float*)d_out;

  char* ws = (char*)d_ws;
  size_t HS = (size_t)NN*OUT*2;                       // 41,984,000 B per h buffer
  _Float16* h0 = (_Float16*)ws;
  _Float16* h1 = (_Float16*)(ws + HS);
  _Float16* h2 = (_Float16*)(ws + 2*HS);
  _Float16* Xt = h1;                                  // overlay: 512*304*224*2 = 69.7 MB
  char* aux = ws + 3*HS;
  float*    Wf = (float*)aux;    aux += (size_t)6*200*600*4;
  _Float16* Bp = (_Float16*)aux; aux += (size_t)6*6*13*224*16*2;   // 3.35 MB
  _Float16* Wp1 = (_Float16*)aux; aux += (size_t)21*64*32*2;
  int* deg    = (int*)aux;       aux += (size_t)NN*4;
  int* part   = (int*)aux;       aux += (size_t)NN*4;
  int* bsum   = (int*)aux;       aux += 256*4;
  int* rowptr = (int*)aux;       aux += (size_t)(NN+16)*4;
  int* cursor = (int*)aux;       aux += (size_t)NN*4;
  int* col    = (int*)aux;       aux += (size_t)NE*4;
  float* sums = (float*)aux;     aux += 128*4;
  float* sc   = (float*)aux;     aux += 64*4;
  float* sh   = (float*)aux;     aux += 64*4;
  float* z_c1  = (float*)aux;
  float* y_c1  = z_c1  + (size_t)512*50*301;
  float* z_mp1 = y_c1  + (size_t)512*50*200;
  float* y_mp1 = z_mp1 + (size_t)512*50*150;
  float* z_c2  = y_mp1 + (size_t)512*50*99;
  float* y_c2  = z_c2  + (size_t)512*20*152;
  float* z_mp2 = y_c2  + (size_t)512*20*101;
  float* y_mp2 = z_mp2 + (size_t)512*1520;

  // precompute
  pad16<<<NN*OUT/256, 256, 0, stream>>>(x, h0);
  fuse_w_kernel<<<(6*200*600+255)/256, 256, 0, stream>>>(ggcw, wih, Wf);
  pack_b32<<<6*6*13*224*16/256, 256, 0, stream>>>(Wf, whh, Bp);
  pack_w1<<<(21*64*32+255)/256, 256, 0, stream>>>(c1w, Wp1);
  // CSR (hierarchical scan)
  zero_i32<<<(NN+255)/256, 256, 0, stream>>>(deg, NN);
  count_deg<<<NE/256, 256, 0, stream>>>(ei, deg);
  scan_block<<<NN/512, 512, 0, stream>>>(deg, part, bsum);
  scan_bsum<<<1, 256, 0, stream>>>(bsum, NN/512);
  scan_add<<<(NN+255)/256, 256, 0, stream>>>(part, bsum, rowptr, cursor);
  fill_csr<<<NE/256, 256, 0, stream>>>(ei, cursor, col);

  // GGC layers
  _Float16* cur = h0; _Float16* other = h2;
  for (int i=0;i<LAYERS;i++){
    gather16<<<NN*25/256, 256, 0, stream>>>(cur, rowptr, col, h1);
    gru_mfma2<<<NN/32, 448, 0, stream>>>(h1, cur, Bp + (size_t)i*6*13*224*16,
                                         bih, bhh, other);
    _Float16* t = cur; cur = other; other = t;
  }
  // cur == h0 (final hidden, fp16); h1/h2 free -> Xt overlay

  // head
  build_xt<<<dim3(7, 10, BATCH), 256, 0, stream>>>(cur, x, Xt);
  conv1_mfma<<<dim3(5, BATCH), 256, 0, stream>>>(Xt, Wp1, c1b, 301, z_c1);
  conv1_mfma<<<dim3(4, BATCH), 256, 0, stream>>>(Xt, Wp1, c1b, 200, y_c1);

  zero_f32<<<1, 128, 0, stream>>>(sums, 128);
  bn_stats<<<dim3(50,16), 256, 0, stream>>>(z_c1, 50, 301, sums);
  bn_finalize<<<1, 64, 0, stream>>>(sums, bn1g, bn1b, 50, 1.f/(512.f*301.f), sc, sh);
  bn_act_pool<<<(512*50*150+255)/256, 256, 0, stream>>>(z_c1, sc, sh, 50, 301, 150, 3, 1, z_mp1);

  zero_f32<<<1, 128, 0, stream>>>(sums, 128);
  bn_stats<<<dim3(50,16), 256, 0, stream>>>(y_c1, 50, 200, sums);
  bn_finalize<<<1, 64, 0, stream>>>(sums, bn1g, bn1b, 50, 1.f/(512.f*200.f), sc, sh);
  bn_act_pool<<<(512*50*99+255)/256, 256, 0, stream>>>(y_c1, sc, sh, 50, 200, 99, 3, 1, y_mp1);

  conv2_kernel<<<BATCH, 256, 0, stream>>>(z_mp1, c2w, c2b, 150, z_c2);
  conv2_kernel<<<BATCH, 256, 0, stream>>>(y_mp1, c2w, c2b, 99, y_c2);

  zero_f32<<<1, 128, 0, stream>>>(sums, 128);
  bn_stats<<<dim3(20,16), 256, 0, stream>>>(z_c2, 20, 152, sums);
  bn_finalize<<<1, 64, 0, stream>>>(sums, bn2g, bn2b, 20, 1.f/(512.f*152.f), sc, sh);
  bn_act_pool<<<(512*20*76+255)/256, 256, 0, stream>>>(z_c2, sc, sh, 20, 152, 76, 2, 0, z_mp2);

  zero_f32<<<1, 128, 0, stream>>>(sums, 128);
  bn_stats<<<dim3(20,16), 256, 0, stream>>>(y_c2, 20, 101, sums);
  bn_finalize<<<1, 64, 0, stream>>>(sums, bn2g, bn2b, 20, 1.f/(512.f*101.f), sc, sh);
  bn_act_pool<<<(512*20*50+255)/256, 256, 0, stream>>>(y_c2, sc, sh, 20, 101, 50, 2, 0, y_mp2);

  final_kernel<<<BATCH, 256, 0, stream>>>(z_mp2, y_mp2, fc1w, fc1b, fc2w, fc2b, out);
}

// Round 7
// 1463.128 us; speedup vs baseline: 16.5465x; 1.0573x over previous
//
#include <hip/hip_runtime.h>
#include <math.h>

#define NN 104960      // nodes = 205 * 512
#define OUT 200
#define EMB 101
#define NPG 205
#define BATCH 512
#define NE 629760      // edges
#define LAYERS 6

typedef _Float16 h8 __attribute__((ext_vector_type(8)));
typedef float f4 __attribute__((ext_vector_type(4)));
typedef float f16v __attribute__((ext_vector_type(16)));

// fast transcendentals on native v_exp_f32 / v_rcp_f32
__device__ __forceinline__ float fsig(float x) {
  return __builtin_amdgcn_rcpf(1.f + __builtin_amdgcn_exp2f(-1.44269504f*x));
}
__device__ __forceinline__ float ftanh(float x) {
  float e = __builtin_amdgcn_exp2f(2.88539008f*x);      // e^(2x)
  return 1.f - 2.f*__builtin_amdgcn_rcpf(e + 1.f);
}

// ---------------- utility kernels ----------------
__global__ void zero_i32(int* p, int n){ int i=blockIdx.x*256+threadIdx.x; if(i<n) p[i]=0; }
__global__ void zero_f32(float* p, int n){ int i=blockIdx.x*blockDim.x+threadIdx.x; if(i<n) p[i]=0.f; }

// h[N,200] fp16 = pad(x[N,101])
__global__ void pad16(const float* __restrict__ x, _Float16* __restrict__ h) {
  int idx = blockIdx.x*256 + threadIdx.x;
  if (idx >= NN*OUT) return;
  int n = idx / OUT, j = idx - n*OUT;
  h[idx] = (j < EMB) ? (_Float16)x[n*EMB + j] : (_Float16)0.f;
}

// Wf[i][k][o] = sum_j ggc_w[i][k][j] * wih[o][j]   (i<6, k<200, o<600)  fp32
__global__ void fuse_w_kernel(const float* __restrict__ ggc_w, const float* __restrict__ wih,
                              float* __restrict__ Wf) {
  long idx = (long)blockIdx.x*256 + threadIdx.x;
  if (idx >= 6L*200*600) return;
  int o = (int)(idx % 600); long r = idx / 600; int k = (int)(r % 200); int i = (int)(r / 200);
  const float* wr = ggc_w + ((long)i*200 + k)*200;
  const float* vr = wih + (long)o*200;
  float acc = 0.f;
  for (int j=0;j<200;j++) acc += wr[j]*vr[j];
  Wf[idx] = acc;
}

// Bp32[layer][gate][s(13)][j(224)][k(16)] fp16 — 32-wide fragment order for 32x32x16 MFMA.
__global__ void pack_b32(const float* __restrict__ Wf, const float* __restrict__ whh,
                         _Float16* __restrict__ Bp) {
  size_t idx = (size_t)blockIdx.x*256 + threadIdx.x;
  if (idx >= 6UL*6*13*224*16) return;
  int kk = (int)(idx & 15); size_t r = idx >> 4;
  int j = (int)(r % 224); r /= 224;
  int s = (int)(r % 13);  r /= 13;
  int g = (int)(r % 6);   int l = (int)(r / 6);
  int k = s*16 + kk;
  float v = 0.f;
  if (k < 200 && j < 200) {
    v = (g < 3) ? Wf[(size_t)l*120000 + (size_t)k*600 + g*200 + j]
                : whh[((size_t)(g-3)*200 + j)*200 + k];
  }
  Bp[idx] = (_Float16)v;
}

// conv1 weights -> fragment order Wp[s(21)][o(64)][kk(32)] fp16
__global__ void pack_w1(const float* __restrict__ w, _Float16* __restrict__ Wp) {
  int idx = blockIdx.x*256 + threadIdx.x;   // 21*64*32 = 43008
  if (idx >= 21*64*32) return;
  int kk = idx & 31; int r = idx >> 5;
  int o = r & 63; int s = r >> 6;
  int kc = s/7, p = (s%7)*32 + kk;
  float v = 0.f;
  if (o < 50 && p < 205) v = w[o*615 + p*3 + kc];
  Wp[idx] = (_Float16)v;
}

// ---------------- CSR build ----------------
__global__ void count_deg(const int* __restrict__ ei, int* __restrict__ cnt) {
  int e = blockIdx.x*256+threadIdx.x;
  if (e < NE) atomicAdd(&cnt[ei[NE + e]], 1);
}

// hierarchical scan: NN = 205 blocks x 512
__global__ __launch_bounds__(512) void scan_block(const int* __restrict__ cnt,
        int* __restrict__ partial, int* __restrict__ bsum) {
  __shared__ int sd[512];
  int gi = blockIdx.x*512 + threadIdx.x;
  int v = cnt[gi];
  sd[threadIdx.x] = v;
  __syncthreads();
  #pragma unroll
  for (int d=1; d<512; d<<=1) {
    int t = (threadIdx.x>=d)? sd[threadIdx.x-d] : 0;
    __syncthreads();
    sd[threadIdx.x] += t;
    __syncthreads();
  }
  partial[gi] = sd[threadIdx.x] - v;              // exclusive within block
  if (threadIdx.x==511) bsum[blockIdx.x] = sd[511];
}

__global__ __launch_bounds__(256) void scan_bsum(int* __restrict__ bsum, int nb) {
  __shared__ int sd[256];
  int v = (threadIdx.x<nb)? bsum[threadIdx.x] : 0;
  sd[threadIdx.x] = v;
  __syncthreads();
  #pragma unroll
  for (int d=1; d<256; d<<=1) {
    int t = (threadIdx.x>=d)? sd[threadIdx.x-d] : 0;
    __syncthreads();
    sd[threadIdx.x] += t;
    __syncthreads();
  }
  if (threadIdx.x<nb) bsum[threadIdx.x] = sd[threadIdx.x] - v;   // exclusive
}

__global__ void scan_add(const int* __restrict__ partial, const int* __restrict__ bsum,
                         int* __restrict__ rowptr, int* __restrict__ cursor) {
  int i = blockIdx.x*256 + threadIdx.x;
  if (i < NN) {
    int v = partial[i] + bsum[i >> 9];
    rowptr[i] = v;
    cursor[i] = v;
  }
  if (i == 0) rowptr[NN] = NE;
}

__global__ void fill_csr(const int* __restrict__ ei, int* __restrict__ cursor, int* __restrict__ col) {
  int e = blockIdx.x*256+threadIdx.x;
  if (e < NE) {
    int dst = ei[NE+e], src = ei[e];
    int pos = atomicAdd(&cursor[dst], 1);
    col[pos] = src;
  }
}

// hagg[n,:] += h[col,:] ; thread = (node, 8-elem chunk), 25 chunks/node
__global__ void gather16(const _Float16* __restrict__ h, const int* __restrict__ rowptr,
                         const int* __restrict__ col, _Float16* __restrict__ out) {
  int idx = blockIdx.x*256 + threadIdx.x;
  if (idx >= NN*25) return;
  int n = idx / 25, c = idx - n*25;
  int s = rowptr[n], e = rowptr[n+1];
  float a[8];
  #pragma unroll
  for (int i=0;i<8;i++) a[i]=0.f;
  for (int p=s; p<e; ++p) {
    const h8 v = *(const h8*)(h + (size_t)col[p]*200 + c*8);
    #pragma unroll
    for (int i=0;i<8;i++) a[i] += (float)v[i];
  }
  h8 o;
  #pragma unroll
  for (int i=0;i<8;i++) o[i] = (_Float16)a[i];
  *(h8*)(out + (size_t)n*200 + c*8) = o;
}

// ---------------- MFMA fused GRU (32x32x16, M=64 with B register reuse) ----------------
// block 448 thr = 7 waves; M = 64 rows; wave w owns j-tile jt=w, all 6 gates,
// and BOTH 32-row halves (one B load feeds 2 MFMAs).
__global__ __launch_bounds__(448) void gru_mfma2(
    const _Float16* __restrict__ hagg, const _Float16* __restrict__ h,
    const _Float16* __restrict__ Bp,
    const float* __restrict__ bih, const float* __restrict__ bhh,
    _Float16* __restrict__ hnew) {
  __shared__ _Float16 As[2][64][232];
  const int tid = threadIdx.x;
  const int bm = blockIdx.x * 64;

  for (int idx = tid; idx < 3200; idx += 448) {     // 2*64*25 h8 chunks
    int m_ = idx / 1600; int rem = idx - m_*1600;
    int row = rem / 25; int kc = rem - row*25;
    const _Float16* src = m_ ? h : hagg;
    *(h8*)&As[m_][row][kc*8] = *(const h8*)(src + (size_t)(bm+row)*200 + kc*8);
  }
  for (int idx = tid; idx < 512; idx += 448) {      // zero pad k = 200..231
    int m_ = idx / 256; int rem = idx - m_*256;
    int row = rem >> 2; int c = rem & 3;
    h8 z;
    #pragma unroll
    for (int i=0;i<8;i++) z[i] = (_Float16)0.f;
    *(h8*)&As[m_][row][200 + c*8] = z;
  }
  __syncthreads();

  const int lane = tid & 63;
  const int jt = tid >> 6;          // 0..6
  const int jcol = lane & 31;
  const int kh = lane >> 5;         // k-half

  f16v accL[6], accH[6];
  #pragma unroll
  for (int g=0;g<6;g++)
    #pragma unroll
    for (int r=0;r<16;r++) { accL[g][r] = 0.f; accH[g][r] = 0.f; }

  const _Float16* bbase = Bp + ((size_t)jt*32 + jcol)*16 + kh*8;
  #pragma unroll 2
  for (int s=0; s<13; s++) {
    const h8 aA0 = *(const h8*)&As[0][jcol][s*16 + kh*8];
    const h8 aA1 = *(const h8*)&As[0][32+jcol][s*16 + kh*8];
    const h8 aH0 = *(const h8*)&As[1][jcol][s*16 + kh*8];
    const h8 aH1 = *(const h8*)&As[1][32+jcol][s*16 + kh*8];
    #pragma unroll
    for (int g=0; g<6; g++) {
      const h8 b = *(const h8*)(bbase + (size_t)(g*13 + s)*224*16);
      accL[g] = __builtin_amdgcn_mfma_f32_32x32x16_f16((g<3)?aA0:aH0, b, accL[g], 0,0,0);
      accH[g] = __builtin_amdgcn_mfma_f32_32x32x16_f16((g<3)?aA1:aH1, b, accH[g], 0,0,0);
    }
  }

  // epilogue: C/D col=lane&31, row=(reg&3)+8*(reg>>2)+4*(lane>>5)
  const int j = jt*32 + jcol;
  if (j < 200) {
    const float bri = bih[j],      brh = bhh[j];
    const float bzi = bih[200+j],  bzh = bhh[200+j];
    const float bni = bih[400+j],  bnh = bhh[400+j];
    #pragma unroll
    for (int r=0;r<16;r++) {
      const int row = (r&3) + 8*(r>>2) + 4*kh;
      {
        const float rr = fsig(accL[0][r]+bri + accL[3][r]+brh);
        const float zz = fsig(accL[1][r]+bzi + accL[4][r]+bzh);
        const float nn = ftanh(accL[2][r]+bni + rr*(accL[5][r]+bnh));
        const float hv = (float)As[1][row][j];
        hnew[(size_t)(bm+row)*200 + j] = (_Float16)((1.f-zz)*nn + zz*hv);
      }
      {
        const float rr = fsig(accH[0][r]+bri + accH[3][r]+brh);
        const float zz = fsig(accH[1][r]+bzi + accH[4][r]+bzh);
        const float nn = ftanh(accH[2][r]+bni + rr*(accH[5][r]+bnh));
        const float hv = (float)As[1][32+row][j];
        hnew[(size_t)(bm+32+row)*200 + j] = (_Float16)((1.f-zz)*nn + zz*hv);
      }
    }
  }
}

// ---------------- head ----------------
__global__ __launch_bounds__(256) void build_xt(const _Float16* __restrict__ hid,
        const float* __restrict__ x, _Float16* __restrict__ Xt) {
  __shared__ _Float16 T[32][34];
  int pt = blockIdx.x*32, lt = blockIdx.y*32, b = blockIdx.z;
  int lo = threadIdx.x & 31;
  int po = threadIdx.x >> 5;
  #pragma unroll
  for (int q=0;q<4;q++) {
    int p = pt + po + q*8;
    int l = lt + lo;
    _Float16 v = (_Float16)0.f;
    if (p < 205 && l < 301) {
      size_t node = (size_t)b*205 + p;
      v = (l < 200) ? hid[node*200 + l] : (_Float16)x[node*101 + (l-200)];
    }
    T[po + q*8][lo] = v;
  }
  __syncthreads();
  #pragma unroll
  for (int q=0;q<4;q++) {
    int l = lt + po + q*8;
    int p = pt + lo;
    if (l < 304)
      Xt[((size_t)b*304 + l)*224 + p] = T[lo][po + q*8];
  }
}

__global__ __launch_bounds__(256) void conv1_mfma(const _Float16* __restrict__ Xt,
        const _Float16* __restrict__ Wp, const float* __restrict__ bias,
        int LIN, float* __restrict__ out) {
  int b = blockIdx.y;
  int t0 = blockIdx.x * 64;
  int lane = threadIdx.x & 63;
  int tt = threadIdx.x >> 6;
  int j = lane & 15;
  int kg = lane >> 4;
  int t = t0 + tt*16 + j;
  f4 acc[4];
  #pragma unroll
  for (int a=0;a<4;a++) { acc[a][0]=0.f; acc[a][1]=0.f; acc[a][2]=0.f; acc[a][3]=0.f; }
  const _Float16* xb = Xt + (size_t)b*304*224;
  #pragma unroll
  for (int s=0; s<21; s++) {
    const int kc = s/7;
    const int p0 = (s - kc*7)*32 + kg*8;
    const int tp = t + kc - 1;
    h8 bfrag = {0,0,0,0,0,0,0,0};
    if (tp >= 0 && tp < LIN) bfrag = *(const h8*)(xb + (size_t)tp*224 + p0);
    #pragma unroll
    for (int a=0;a<4;a++) {
      const h8 afrag = *(const h8*)(Wp + ((size_t)(s*64 + a*16 + j)*32 + kg*8));
      acc[a] = __builtin_amdgcn_mfma_f32_16x16x32_f16(afrag, bfrag, acc[a], 0,0,0);
    }
  }
  if (t < LIN) {
    #pragma unroll
    for (int a=0;a<4;a++) {
      #pragma unroll
      for (int r=0;r<4;r++) {
        int o = a*16 + kg*4 + r;
        if (o < 50) out[((size_t)b*50 + o)*LIN + t] = acc[a][r] + bias[o];
      }
    }
  }
}

__global__ void bn_stats(const float* __restrict__ v, int C, int L, float* __restrict__ sums) {
  int c = blockIdx.x;
  int bs = blockIdx.y * 32;
  float s = 0.f, s2 = 0.f;
  for (int idx = threadIdx.x; idx < 32*L; idx += 256) {
    int b = bs + idx / L, t = idx - (idx/L)*L;
    float val = v[((long)b*C + c)*L + t];
    s += val; s2 += val*val;
  }
  __shared__ float rs[256], rq[256];
  rs[threadIdx.x]=s; rq[threadIdx.x]=s2; __syncthreads();
  for (int d=128; d>0; d>>=1){
    if (threadIdx.x<d){ rs[threadIdx.x]+=rs[threadIdx.x+d]; rq[threadIdx.x]+=rq[threadIdx.x+d]; }
    __syncthreads();
  }
  if (threadIdx.x==0){ atomicAdd(&sums[2*c], rs[0]); atomicAdd(&sums[2*c+1], rq[0]); }
}

__global__ void bn_finalize(const float* __restrict__ sums, const float* __restrict__ g,
        const float* __restrict__ b, int C, float inv_n, float* __restrict__ scale, float* __restrict__ shift) {
  int c = threadIdx.x;
  if (c < C) {
    float mean = sums[2*c]*inv_n;
    float var = sums[2*c+1]*inv_n - mean*mean;
    float sc = g[c]*rsqrtf(var + 1e-5f);
    scale[c] = sc;
    shift[c] = b[c] - mean*sc;
  }
}

__global__ void bn_act_pool(const float* __restrict__ v, const float* __restrict__ sc,
      const float* __restrict__ sh, int C, int Lin, int Lout, int K, int do_relu, float* __restrict__ out) {
  int idx = blockIdx.x*256 + threadIdx.x;
  int total = BATCH*C*Lout;
  if (idx>=total) return;
  int t = idx % Lout; int r = idx / Lout; int c = r % C; int b = r / C;
  const float* src = v + ((long)(b*C + c))*Lin + 2*t;
  float m = -3.4e38f;
  for (int k=0;k<K;k++){
    float u = src[k]*sc[c] + sh[c];
    if (do_relu) u = (u>=0.f)? u : 0.01f*u;
    m = fmaxf(m,u);
  }
  out[idx] = m;
}

__global__ __launch_bounds__(256) void conv2_kernel(const float* __restrict__ in,
        const float* __restrict__ w, const float* __restrict__ b2, int Lm, float* __restrict__ out) {
  __shared__ float sw[1000];
  __shared__ float sin[50*150];
  int b = blockIdx.x;
  for (int i=threadIdx.x;i<1000;i+=256) sw[i]=w[i];
  for (int i=threadIdx.x;i<50*Lm;i+=256) sin[i] = in[(long)b*50*Lm + i];
  __syncthreads();
  int Lo = Lm + 2;
  for (int idx=threadIdx.x; idx<20*Lo; idx+=256) {
    int c = idx / Lo, t = idx - c*Lo;
    float acc = b2[c];
    if (t>=1 && t<=Lm) {
      const float* sp = sin + (t-1);
      const float* wp = sw + c*50;
      for (int i=0;i<50;i++) acc += wp[i]*sp[i*Lm];
    }
    out[(long)b*20*Lo + idx] = acc;
  }
}

__global__ void final_kernel(const float* __restrict__ Zf, const float* __restrict__ Yf,
        const float* __restrict__ fc1w, const float* __restrict__ fc1b,
        const float* __restrict__ fc2w, const float* __restrict__ fc2b, float* __restrict__ out) {
  int b = blockIdx.x;
  float s1=0.f, s2=0.f;
  for (int i=threadIdx.x;i<1520;i+=256) s1 += Zf[(long)b*1520+i]*fc1w[i];
  for (int i=threadIdx.x;i<1000;i+=256) s2 += Yf[(long)b*1000+i]*fc2w[i];
  __shared__ float r1[256], r2[256];
  r1[threadIdx.x]=s1; r2[threadIdx.x]=s2; __syncthreads();
  for (int d=128; d>0; d>>=1){
    if (threadIdx.x<d){ r1[threadIdx.x]+=r1[threadIdx.x+d]; r2[threadIdx.x]+=r2[threadIdx.x+d]; }
    __syncthreads();
  }
  if (threadIdx.x==0){
    float res = (r1[0]+fc1b[0])*(r2[0]+fc2b[0]);
    out[b] = fsig(res);
  }
}

// ---------------- launch ----------------
extern "C" void kernel_launch(void* const* d_in, const int* in_sizes, int n_in,
                              void* d_out, int out_size, void* d_ws, size_t ws_size,
                              hipStream_t stream) {
  const float* x    = (const float*)d_in[0];
  const int*   ei   = (const int*)d_in[1];
  const float* ggcw = (const float*)d_in[2];
  const float* wih  = (const float*)d_in[3];
  const float* whh  = (const float*)d_in[4];
  const float* bih  = (const float*)d_in[5];
  const float* bhh  = (const float*)d_in[6];
  const float* c1w  = (const float*)d_in[7];
  const float* c1b  = (const float*)d_in[8];
  const float* bn1g = (const float*)d_in[9];
  const float* bn1b = (const float*)d_in[10];
  const float* c2w  = (const float*)d_in[11];
  const float* c2b  = (const float*)d_in[12];
  const float* bn2g = (const float*)d_in[13];
  const float* bn2b = (const float*)d_in[14];
  const float* fc1w = (const float*)d_in[15];
  const float* fc1b = (const float*)d_in[16];
  const float* fc2w = (const float*)d_in[17];
  const float* fc2b = (const float*)d_in[18];
  float* out = (float*)d_out;

  char* ws = (char*)d_ws;
  size_t HS = (size_t)NN*OUT*2;                       // 41,984,000 B per h buffer
  _Float16* h0 = (_Float16*)ws;
  _Float16* h1 = (_Float16*)(ws + HS);
  _Float16* h2 = (_Float16*)(ws + 2*HS);
  _Float16* Xt = h1;                                  // overlay: 512*304*224*2 = 69.7 MB
  char* aux = ws + 3*HS;
  float*    Wf = (float*)aux;    aux += (size_t)6*200*600*4;
  _Float16* Bp = (_Float16*)aux; aux += (size_t)6*6*13*224*16*2;   // 3.35 MB
  _Float16* Wp1 = (_Float16*)aux; aux += (size_t)21*64*32*2;
  int* deg    = (int*)aux;       aux += (size_t)NN*4;
  int* part   = (int*)aux;       aux += (size_t)NN*4;
  int* bsum   = (int*)aux;       aux += 256*4;
  int* rowptr = (int*)aux;       aux += (size_t)(NN+16)*4;
  int* cursor = (int*)aux;       aux += (size_t)NN*4;
  int* col    = (int*)aux;       aux += (size_t)NE*4;
  float* sums = (float*)aux;     aux += 128*4;
  float* sc   = (float*)aux;     aux += 64*4;
  float* sh   = (float*)aux;     aux += 64*4;
  float* z_c1  = (float*)aux;
  float* y_c1  = z_c1  + (size_t)512*50*301;
  float* z_mp1 = y_c1  + (size_t)512*50*200;
  float* y_mp1 = z_mp1 + (size_t)512*50*150;
  float* z_c2  = y_mp1 + (size_t)512*50*99;
  float* y_c2  = z_c2  + (size_t)512*20*152;
  float* z_mp2 = y_c2  + (size_t)512*20*101;
  float* y_mp2 = z_mp2 + (size_t)512*1520;

  // precompute
  pad16<<<NN*OUT/256, 256, 0, stream>>>(x, h0);
  fuse_w_kernel<<<(6*200*600+255)/256, 256, 0, stream>>>(ggcw, wih, Wf);
  pack_b32<<<6*6*13*224*16/256, 256, 0, stream>>>(Wf, whh, Bp);
  pack_w1<<<(21*64*32+255)/256, 256, 0, stream>>>(c1w, Wp1);
  // CSR (hierarchical scan)
  zero_i32<<<(NN+255)/256, 256, 0, stream>>>(deg, NN);
  count_deg<<<NE/256, 256, 0, stream>>>(ei, deg);
  scan_block<<<NN/512, 512, 0, stream>>>(deg, part, bsum);
  scan_bsum<<<1, 256, 0, stream>>>(bsum, NN/512);
  scan_add<<<(NN+255)/256, 256, 0, stream>>>(part, bsum, rowptr, cursor);
  fill_csr<<<NE/256, 256, 0, stream>>>(ei, cursor, col);

  // GGC layers
  _Float16* cur = h0; _Float16* other = h2;
  for (int i=0;i<LAYERS;i++){
    gather16<<<NN*25/256, 256, 0, stream>>>(cur, rowptr, col, h1);
    gru_mfma2<<<NN/64, 448, 0, stream>>>(h1, cur, Bp + (size_t)i*6*13*224*16,
                                         bih, bhh, other);
    _Float16* t = cur; cur = other; other = t;
  }
  // cur == h0 (final hidden, fp16); h1/h2 free -> Xt overlay

  // head
  build_xt<<<dim3(7, 10, BATCH), 256, 0, stream>>>(cur, x, Xt);
  conv1_mfma<<<dim3(5, BATCH), 256, 0, stream>>>(Xt, Wp1, c1b, 301, z_c1);
  conv1_mfma<<<dim3(4, BATCH), 256, 0, stream>>>(Xt, Wp1, c1b, 200, y_c1);

  zero_f32<<<1, 128, 0, stream>>>(sums, 128);
  bn_stats<<<dim3(50,16), 256, 0, stream>>>(z_c1, 50, 301, sums);
  bn_finalize<<<1, 64, 0, stream>>>(sums, bn1g, bn1b, 50, 1.f/(512.f*301.f), sc, sh);
  bn_act_pool<<<(512*50*150+255)/256, 256, 0, stream>>>(z_c1, sc, sh, 50, 301, 150, 3, 1, z_mp1);

  zero_f32<<<1, 128, 0, stream>>>(sums, 128);
  bn_stats<<<dim3(50,16), 256, 0, stream>>>(y_c1, 50, 200, sums);
  bn_finalize<<<1, 64, 0, stream>>>(sums, bn1g, bn1b, 50, 1.f/(512.f*200.f), sc, sh);
  bn_act_pool<<<(512*50*99+255)/256, 256, 0, stream>>>(y_c1, sc, sh, 50, 200, 99, 3, 1, y_mp1);

  conv2_kernel<<<BATCH, 256, 0, stream>>>(z_mp1, c2w, c2b, 150, z_c2);
  conv2_kernel<<<BATCH, 256, 0, stream>>>(y_mp1, c2w, c2b, 99, y_c2);

  zero_f32<<<1, 128, 0, stream>>>(sums, 128);
  bn_stats<<<dim3(20,16), 256, 0, stream>>>(z_c2, 20, 152, sums);
  bn_finalize<<<1, 64, 0, stream>>>(sums, bn2g, bn2b, 20, 1.f/(512.f*152.f), sc, sh);
  bn_act_pool<<<(512*20*76+255)/256, 256, 0, stream>>>(z_c2, sc, sh, 20, 152, 76, 2, 0, z_mp2);

  zero_f32<<<1, 128, 0, stream>>>(sums, 128);
  bn_stats<<<dim3(20,16), 256, 0, stream>>>(y_c2, 20, 101, sums);
  bn_finalize<<<1, 64, 0, stream>>>(sums, bn2g, bn2b, 20, 1.f/(512.f*101.f), sc, sh);
  bn_act_pool<<<(512*20*50+255)/256, 256, 0, stream>>>(y_c2, sc, sh, 20, 101, 50, 2, 0, y_mp2);

  final_kernel<<<BATCH, 256, 0, stream>>>(z_mp2, y_mp2, fc1w, fc1b, fc2w, fc2b, out);
}